// Round 2
// baseline (295.656 us; speedup 1.0000x reference)
//
#include <hip/hip_runtime.h>

// Shapes: B=64, N=197, C=768, H=12, hd=64
// Both GEMMs: 256x256 tile, BK=64, 512 thr / 8 waves (2Mx4N), 128 KiB LDS
// double-buffer, counted-vmcnt deep pipeline (vmcnt never drained to 0 in
// the main loop), 4 phases/K-tile with setprio(1) around MFMA clusters,
// XOR-swizzled LDS (pre-swizzled global source + swizzled ds_read).
// Attention: MFMA flash-lite, bias pre-gathered in fragment layout.

#define NB   64
#define NN   197
#define NC   768
#define NH   12
#define HD   64
#define MM   (NB*NN)      // 12608
#define MR   12800        // 50*256
#define NP   208          // 13*16
#define SZQ  ((size_t)NB * NH * NN * HD)

typedef unsigned short ushort_t;
typedef __attribute__((ext_vector_type(8))) short short8;
typedef __attribute__((ext_vector_type(4))) float f32x4;
union U128 { uint4 u; short8 s; };

__device__ __forceinline__ unsigned bf16_rne(float f) {
    unsigned u = __float_as_uint(f);
    return (u + 0x7fffu + ((u >> 16) & 1u)) >> 16;
}

__device__ __forceinline__ void gld16(unsigned short* lds, const unsigned short* g) {
    __builtin_amdgcn_global_load_lds(
        (const __attribute__((address_space(1))) void*)g,
        (__attribute__((address_space(3))) void*)lds, 16, 0, 0);
}

// raw barrier (no vmcnt drain) with compiler memory fences on both sides so
// LDS reads/writes cannot be hoisted/sunk across it.
#define BAR() do { asm volatile("" ::: "memory"); \
                   __builtin_amdgcn_s_barrier();  \
                   asm volatile("" ::: "memory"); } while (0)

// ---------------------------------------------------------------------------
// Converts: x -> xh, w_qkv -> wh, w_proj -> wp (all bf16 hi, stride NC)
// ---------------------------------------------------------------------------
__global__ __launch_bounds__(256) void convert_all(
    const float* __restrict__ x, const float* __restrict__ w_qkv,
    const float* __restrict__ w_proj,
    ushort_t* __restrict__ xh, ushort_t* __restrict__ wh,
    ushort_t* __restrict__ wp)
{
    int idx = blockIdx.x * 256 + threadIdx.x;
    if (idx >= (MM + 2304 + 768) * 192) return;
    int r = idx / 192;
    int c = (idx - r * 192) * 4;
    const float* src;
    ushort_t* dsth;
    if (r < MM) {
        src = x + (size_t)r * NC; dsth = xh + (size_t)r * NC + c;
    } else if (r < MM + 2304) {
        int rr = r - MM;
        src = w_qkv + (size_t)rr * NC; dsth = wh + (size_t)rr * NC + c;
    } else {
        int rr = r - MM - 2304;
        src = w_proj + (size_t)rr * NC; dsth = wp + (size_t)rr * NC + c;
    }
    float4 f = *(const float4*)(src + c);
    ushort4 hv = { (ushort_t)bf16_rne(f.x), (ushort_t)bf16_rne(f.y),
                   (ushort_t)bf16_rne(f.z), (ushort_t)bf16_rne(f.w) };
    *(ushort4*)dsth = hv;
}

// ---------------------------------------------------------------------------
// biasP in MFMA C-fragment layout: [h][qt][kt][quad][l15][r] f32.
// ---------------------------------------------------------------------------
__global__ __launch_bounds__(256) void bias_precompute(
    const float* __restrict__ table, const int* __restrict__ rel_index,
    float* __restrict__ biasP)
{
    int i = blockIdx.x * 256 + threadIdx.x;
    if (i >= NH * 13 * 13 * 256) return;
    int r = i & 3, l15 = (i >> 2) & 15, quad = (i >> 6) & 3;
    int t = i >> 8;
    int kt = t % 13; int t2 = t / 13;
    int qt = t2 % 13; int h = t2 / 13;
    int n = qt * 16 + quad * 4 + r;
    int m = kt * 16 + l15;
    float v = -1e30f;
    if (n < NN && m < NN) v = table[rel_index[n * NN + m] * NH + h];
    biasP[i] = v;
}

// ---------------------------------------------------------------------------
// 256x256 BK=64 deep-pipelined bf16 MFMA mainloop. 512 threads, 8 waves
// (wm = w&1 -> M half 128 rows, wn = w>>1 -> N quarter 64 cols).
// Per K-tile: 8 gld16/thread staged as 4 chunks; chunk0 of tile t+1 issued
// before a counted s_waitcnt vmcnt(2); chunks 1..3 issued inside phases.
// 4 phases x {8|4 ds_read_b128 -> barrier -> 16 MFMA}.
// ---------------------------------------------------------------------------
__device__ __forceinline__ void gemm256_loop(
    const ushort_t* __restrict__ A2, int sA,
    const ushort_t* __restrict__ B2, int sB,
    int m0, int n0, int kiters,
    ushort_t* Abuf, ushort_t* Bbuf, f32x4 (&acc)[8][4])
{
    const int tid = threadIdx.x;
    const int w = tid >> 6, lane = tid & 63;
    const int wm = w & 1, wn = w >> 1;
    const int lr = lane >> 3, lc = lane & 7;
    const int gch = lc ^ lr;
    const int quad = lane >> 4, l15 = lane & 15;

    const ushort_t* Ag = A2 + (size_t)(m0 + w * 32 + lr) * sA + gch * 8;
    const ushort_t* Bg = B2 + (size_t)(n0 + w * 32 + lr) * sB + gch * 8;

    const int sw = (quad ^ (l15 & 7)) << 3;
    int aoff[8], boff[4];
    #pragma unroll
    for (int i = 0; i < 8; i++) aoff[i] = (wm * 128 + i * 16 + l15) * 64 + sw;
    #pragma unroll
    for (int j = 0; j < 4; j++) boff[j] = (wn * 64 + j * 16 + l15) * 64 + sw;

    // prologue: stage tile 0 fully into buffer 0 (8 gld16/thread)
    {
        ushort_t* Al = Abuf + (w * 32) * 64;
        ushort_t* Bl = Bbuf + (w * 32) * 64;
        #pragma unroll
        for (int c = 0; c < 4; c++) {
            gld16(Al + c * 8 * 64, Ag + (size_t)c * 8 * sA);
            gld16(Bl + c * 8 * 64, Bg + (size_t)c * 8 * sB);
        }
    }

    #define MFMA16(I0) do { \
        __builtin_amdgcn_s_setprio(1); \
        _Pragma("unroll") \
        for (int i_ = 0; i_ < 4; i_++) \
            _Pragma("unroll") \
            for (int j_ = 0; j_ < 4; j_++) \
                acc[(I0) + i_][j_] = __builtin_amdgcn_mfma_f32_16x16x32_bf16( \
                    af[i_].s, bf[j_].s, acc[(I0) + i_][j_], 0, 0, 0); \
        __builtin_amdgcn_s_setprio(0); } while (0)

    for (int t = 0; t < kiters; ++t) {
        const int cur = t & 1;
        const ushort_t* Ac = Abuf + cur * 16384;
        const ushort_t* Bc = Bbuf + cur * 16384;
        ushort_t* An = Abuf + (cur ^ 1) * 16384 + (w * 32) * 64;
        ushort_t* Bn = Bbuf + (cur ^ 1) * 16384 + (w * 32) * 64;
        const ushort_t* AgN = Ag + (size_t)(t + 1) * 64;
        const ushort_t* BgN = Bg + (size_t)(t + 1) * 64;
        const bool pf = (t + 1 < kiters);

        if (pf) {
            gld16(An, AgN);                    // chunk 0 of tile t+1
            gld16(Bn, BgN);
            asm volatile("s_waitcnt vmcnt(2)" ::: "memory");  // tile t landed
        } else {
            asm volatile("s_waitcnt vmcnt(0)" ::: "memory");
        }
        BAR();                                 // tile t visible to all waves

        U128 af[4], bf[4];
        // phase 0: k0=0, A rows 0..3 + all B(k0=0)
        #pragma unroll
        for (int j = 0; j < 4; j++) bf[j].u = *(const uint4*)&Bc[boff[j]];
        #pragma unroll
        for (int i = 0; i < 4; i++) af[i].u = *(const uint4*)&Ac[aoff[i]];
        if (pf) { gld16(An + 8 * 64, AgN + (size_t)8 * sA);
                  gld16(Bn + 8 * 64, BgN + (size_t)8 * sB); }
        BAR();
        MFMA16(0);

        // phase 1: k0=0, A rows 4..7
        #pragma unroll
        for (int i = 0; i < 4; i++) af[i].u = *(const uint4*)&Ac[aoff[4 + i]];
        if (pf) { gld16(An + 16 * 64, AgN + (size_t)16 * sA);
                  gld16(Bn + 16 * 64, BgN + (size_t)16 * sB); }
        BAR();
        MFMA16(4);

        // phase 2: k0=1, A rows 0..3 + all B(k0=1)
        #pragma unroll
        for (int j = 0; j < 4; j++) bf[j].u = *(const uint4*)&Bc[boff[j] ^ 32];
        #pragma unroll
        for (int i = 0; i < 4; i++) af[i].u = *(const uint4*)&Ac[aoff[i] ^ 32];
        if (pf) { gld16(An + 24 * 64, AgN + (size_t)24 * sA);
                  gld16(Bn + 24 * 64, BgN + (size_t)24 * sB); }
        BAR();
        MFMA16(0);

        // phase 3: k0=1, A rows 4..7
        #pragma unroll
        for (int i = 0; i < 4; i++) af[i].u = *(const uint4*)&Ac[aoff[4 + i] ^ 32];
        BAR();
        MFMA16(4);

        BAR();   // all waves done reading buf[cur]; safe to restage next iter
    }
    #undef MFMA16
}

// GEMM1: xh[MR,768] * wh[2304,768]^T -> qbf (scaled), kbf, vbf.
// grid: 450 blocks (50 m-tiles x 9 n-tiles), XCD-bijective remap.
__global__ __launch_bounds__(512) void gemm_qkv_mfma(
    const ushort_t* __restrict__ A2, const ushort_t* __restrict__ B2,
    ushort_t* __restrict__ qbf, ushort_t* __restrict__ kbf,
    ushort_t* __restrict__ vbf)
{
    __shared__ ushort_t Abuf[2 * 16384];
    __shared__ ushort_t Bbuf[2 * 16384];
    f32x4 acc[8][4];
    f32x4 z = {0.f, 0.f, 0.f, 0.f};
    #pragma unroll
    for (int i = 0; i < 8; i++)
        #pragma unroll
        for (int j = 0; j < 4; j++) acc[i][j] = z;

    // XCD-bijective remap: 450 = 8*56 + 2
    const int NWG = 450, NTN = 9;
    int bid = blockIdx.x;
    int q8 = NWG >> 3, r8 = NWG & 7;
    int xcd = bid & 7, loc = bid >> 3;
    int nid = (xcd < r8 ? xcd * (q8 + 1) : r8 * (q8 + 1) + (xcd - r8) * q8) + loc;
    int mt = nid / NTN, nt = nid - mt * NTN;
    const int m0 = mt * 256, n0 = nt * 256;

    gemm256_loop(A2, NC, B2, NC, m0, n0, 12, Abuf, Bbuf, acc);

    const int tid = threadIdx.x;
    const int w = tid >> 6, lane = tid & 63;
    const int wm = w & 1, wn = w >> 1;
    const int quad = lane >> 4, l15 = lane & 15;

    int mbase[8][4];
    bool mval[8][4];
    #pragma unroll
    for (int i = 0; i < 8; i++) {
        #pragma unroll
        for (int r = 0; r < 4; r++) {
            int m = m0 + wm * 128 + i * 16 + quad * 4 + r;
            mval[i][r] = (m < MM);
            int mc = mval[i][r] ? m : 0;
            int b_ = mc / NN, n_ = mc - b_ * NN;
            mbase[i][r] = b_ * NH * NN + n_;
        }
    }
    #pragma unroll
    for (int j = 0; j < 4; j++) {
        int c0 = n0 + wn * 64 + j * 16;
        int tq = c0 / NC;
        int wi = c0 - tq * NC;
        int hh = wi >> 6;
        int d0 = (wi & 63) + l15;
        ushort_t* dst = (tq == 0) ? qbf : (tq == 1) ? kbf : vbf;
        float scale = (tq == 0) ? 0.125f : 1.0f;
        int hoff = hh * (NN * HD) + d0;
        #pragma unroll
        for (int i = 0; i < 8; i++) {
            #pragma unroll
            for (int r = 0; r < 4; r++) {
                if (mval[i][r])
                    dst[(size_t)mbase[i][r] * HD + hoff] =
                        (ushort_t)bf16_rne(acc[i][j][r] * scale);
            }
        }
    }
}

// GEMM2: ab[MR,768] * wp[768,768]^T + bias -> out fp32. 150 blocks (50x3).
__global__ __launch_bounds__(512) void gemm_proj_mfma(
    const ushort_t* __restrict__ A2, const ushort_t* __restrict__ B2,
    const float* __restrict__ bias, float* __restrict__ out)
{
    __shared__ ushort_t Abuf[2 * 16384];
    __shared__ ushort_t Bbuf[2 * 16384];
    f32x4 acc[8][4];
    f32x4 z = {0.f, 0.f, 0.f, 0.f};
    #pragma unroll
    for (int i = 0; i < 8; i++)
        #pragma unroll
        for (int j = 0; j < 4; j++) acc[i][j] = z;

    // XCD-bijective remap: 150 = 8*18 + 6
    const int NWG = 150, NTN = 3;
    int bid = blockIdx.x;
    int q8 = NWG >> 3, r8 = NWG & 7;
    int xcd = bid & 7, loc = bid >> 3;
    int nid = (xcd < r8 ? xcd * (q8 + 1) : r8 * (q8 + 1) + (xcd - r8) * q8) + loc;
    int mt = nid / NTN, nt = nid - mt * NTN;
    const int m0 = mt * 256, n0 = nt * 256;

    gemm256_loop(A2, NC, B2, NC, m0, n0, 12, Abuf, Bbuf, acc);

    const int tid = threadIdx.x;
    const int w = tid >> 6, lane = tid & 63;
    const int wm = w & 1, wn = w >> 1;
    const int quad = lane >> 4, l15 = lane & 15;
    #pragma unroll
    for (int j = 0; j < 4; j++) {
        int col = n0 + wn * 64 + j * 16 + l15;
        float bi = bias[col];
        #pragma unroll
        for (int i = 0; i < 8; i++) {
            #pragma unroll
            for (int r = 0; r < 4; r++) {
                int m = m0 + wm * 128 + i * 16 + quad * 4 + r;
                if (m < MM)
                    out[(size_t)m * NC + col] = acc[i][j][r] + bi;
            }
        }
    }
}

// ---------------------------------------------------------------------------
// MFMA attention. grid (768, 2) x 256 threads (4 waves). Unchanged.
// ---------------------------------------------------------------------------
__global__ __launch_bounds__(256) void attn_mfma(
    const ushort_t* __restrict__ qbf, const ushort_t* __restrict__ kbf,
    const ushort_t* __restrict__ vbf, const float* __restrict__ biasP,
    ushort_t* __restrict__ ab)
{
    __shared__ ushort_t Vt[64 * 232];        // Vt[d][key], 29696 B
    __shared__ ushort_t Pl[4][16 * 232];     // per-wave P / V-stage / O-transpose

    const int bh = blockIdx.x;
    const int b = bh / NH, h = bh % NH;
    const int tid = threadIdx.x;
    const int w = tid >> 6, lane = tid & 63;
    const int quad = lane >> 4, l15 = lane & 15;
    const size_t base = (size_t)bh * (NN * HD);
    const ushort_t* kg = kbf + base;
    const ushort_t* vg = vbf + base;
    const ushort_t* qg = qbf + base;

    // stage V row-major coalesced, then LDS->LDS transpose into Vt
    ushort_t* Vstage = &Pl[0][0];            // 208*64 = 13312 <= 14848
    for (int idx = tid; idx < NP * 8; idx += 256) {
        int row = idx >> 3, ch = idx & 7;
        uint4 val = {0u, 0u, 0u, 0u};
        if (row < NN) val = *(const uint4*)(vg + (size_t)row * HD + ch * 8);
        *(uint4*)&Vstage[row * HD + ch * 8] = val;
    }
    __syncthreads();
    for (int task = tid; task < 64 * 29; task += 256) {
        int d = task & 63, kc = task >> 6;
        ushort_t tmp[8];
        #pragma unroll
        for (int j = 0; j < 8; j++) {
            int key = kc * 8 + j;
            tmp[j] = (key < NP) ? Vstage[key * HD + d] : (ushort_t)0;
        }
        uint4 u;
        u.x = (unsigned)tmp[0] | ((unsigned)tmp[1] << 16);
        u.y = (unsigned)tmp[2] | ((unsigned)tmp[3] << 16);
        u.z = (unsigned)tmp[4] | ((unsigned)tmp[5] << 16);
        u.w = (unsigned)tmp[6] | ((unsigned)tmp[7] << 16);
        *(uint4*)&Vt[d * 232 + kc * 8] = u;
    }
    __syncthreads();                         // Vt ready; Pl free

    const int worker = blockIdx.y * 4 + w;   // 0..7

    #pragma unroll
    for (int rep = 0; rep < 2; rep++) {
        int qt = worker + rep * 8;
        if (qt > 12) break;
        const int q0 = qt * 16;

        int qrow = q0 + l15; if (qrow > NN - 1) qrow = NN - 1;
        U128 qf0, qf1;
        qf0.u = *(const uint4*)(qg + (size_t)qrow * HD + quad * 8);
        qf1.u = *(const uint4*)(qg + (size_t)qrow * HD + 32 + quad * 8);

        // S init from biasP: one coalesced float4 per kt
        f32x4 S[13];
        const float* bp = biasP + ((size_t)(h * 13 + qt) * 13) * 256 + (quad << 6) + (l15 << 2);
        #pragma unroll
        for (int kt = 0; kt < 13; kt++) {
            float4 bv = *(const float4*)(bp + kt * 256);
            S[kt][0] = bv.x; S[kt][1] = bv.y; S[kt][2] = bv.z; S[kt][3] = bv.w;
        }

        // QK^T: 2 MFMAs per kt (Q plain bf16)
        #pragma unroll
        for (int kt = 0; kt < 13; kt++) {
            int krow = kt * 16 + l15; if (krow > NN - 1) krow = NN - 1;
            U128 k0, k1;
            k0.u = *(const uint4*)(kg + (size_t)krow * HD + quad * 8);
            k1.u = *(const uint4*)(kg + (size_t)krow * HD + 32 + quad * 8);
            S[kt] = __builtin_amdgcn_mfma_f32_16x16x32_bf16(qf0.s, k0.s, S[kt], 0, 0, 0);
            S[kt] = __builtin_amdgcn_mfma_f32_16x16x32_bf16(qf1.s, k1.s, S[kt], 0, 0, 0);
        }

        // softmax (rows quad*4+r over 16 l15 lanes x 13 tiles)
        ushort_t* P = Pl[w];
        #pragma unroll
        for (int r = 0; r < 4; r++) {
            float mx = S[0][r];
            #pragma unroll
            for (int kt = 1; kt < 13; kt++) mx = fmaxf(mx, S[kt][r]);
            mx = fmaxf(mx, __shfl_xor(mx, 1));
            mx = fmaxf(mx, __shfl_xor(mx, 2));
            mx = fmaxf(mx, __shfl_xor(mx, 4));
            mx = fmaxf(mx, __shfl_xor(mx, 8));
            float sum = 0.f;
            #pragma unroll
            for (int kt = 0; kt < 13; kt++) {
                float e = __expf(S[kt][r] - mx);
                S[kt][r] = e;
                sum += e;
            }
            sum += __shfl_xor(sum, 1);
            sum += __shfl_xor(sum, 2);
            sum += __shfl_xor(sum, 4);
            sum += __shfl_xor(sum, 8);
            float inv = 1.0f / sum;
            int prow = quad * 4 + r;
            #pragma unroll
            for (int kt = 0; kt < 13; kt++)
                P[prow * 232 + kt * 16 + l15] = (ushort_t)bf16_rne(S[kt][r] * inv);
        }
        // zero P keys 208..231
        #pragma unroll
        for (int z = 0; z < 3; z++) {
            int idx = z * 64 + lane;
            int row = idx / 12, c = idx - row * 12;
            *(unsigned*)&P[row * 232 + NP + 2 * c] = 0u;
        }

        // PV
        f32x4 O[4];
        f32x4 z4 = {0.f, 0.f, 0.f, 0.f};
        #pragma unroll
        for (int dt = 0; dt < 4; dt++) O[dt] = z4;
        #pragma unroll
        for (int ks = 0; ks < 7; ks++) {
            U128 pf;
            pf.u = *(const uint4*)&P[l15 * 232 + ks * 32 + quad * 8];
            #pragma unroll
            for (int dt = 0; dt < 4; dt++) {
                U128 vf;
                vf.u = *(const uint4*)&Vt[(dt * 16 + l15) * 232 + ks * 32 + quad * 8];
                O[dt] = __builtin_amdgcn_mfma_f32_16x16x32_bf16(pf.s, vf.s, O[dt], 0, 0, 0);
            }
        }

        // epilogue: transpose O through wave-private LDS, emit b128 bf16 hi
        float* Osh = (float*)&Pl[w][0];      // stride 68 floats (16B-aligned rows)
        #pragma unroll
        for (int dt = 0; dt < 4; dt++)
            #pragma unroll
            for (int r = 0; r < 4; r++)
                Osh[(quad * 4 + r) * 68 + dt * 16 + l15] = O[dt][r];
        int orow = lane >> 2;
        int d0 = (lane & 3) << 4;
        int q = q0 + orow;
        if (q < NN) {
            unsigned hiw[8];
            #pragma unroll
            for (int k4 = 0; k4 < 4; k4++) {
                float4 f = *(const float4*)&Osh[orow * 68 + d0 + k4 * 4];
                unsigned h0 = bf16_rne(f.x), h1 = bf16_rne(f.y);
                unsigned h2 = bf16_rne(f.z), h3 = bf16_rne(f.w);
                hiw[k4 * 2]     = h0 | (h1 << 16);
                hiw[k4 * 2 + 1] = h2 | (h3 << 16);
            }
            size_t baseo = ((size_t)b * NN + q) * NC + h * HD + d0;
            uint4 hA = {hiw[0], hiw[1], hiw[2], hiw[3]};
            uint4 hB = {hiw[4], hiw[5], hiw[6], hiw[7]};
            *(uint4*)&ab[baseo] = hA;
            *(uint4*)&ab[baseo + 8] = hB;
        }
    }
}

// ---------------------------------------------------------------------------
extern "C" void kernel_launch(void* const* d_in, const int* in_sizes, int n_in,
                              void* d_out, int out_size, void* d_ws, size_t ws_size,
                              hipStream_t stream)
{
    const float* x        = (const float*)d_in[0];
    const float* table    = (const float*)d_in[1];
    const float* w_qkv    = (const float*)d_in[2];
    const float* w_proj   = (const float*)d_in[3];
    const float* b_proj   = (const float*)d_in[4];
    const int*   rel_idx  = (const int*)d_in[5];
    float* out = (float*)d_out;

    ushort_t* xh  = (ushort_t*)d_ws;                        // MR*768
    ushort_t* wh  = xh + (size_t)MR * NC;                   // 2304*768
    ushort_t* wp  = wh + (size_t)2304 * NC;                 // 768*768
    ushort_t* ab  = wp + (size_t)768 * NC;                  // MR*768
    ushort_t* qbf = ab + (size_t)MR * NC;                   // SZQ each
    ushort_t* kbf = qbf + SZQ;
    ushort_t* vbf = kbf + SZQ;
    float* biasP  = (float*)(vbf + SZQ);                    // 12*13*13*256 f32

    const int cvt_quads = (MM + 2304 + 768) * 192;
    convert_all<<<(cvt_quads + 255) / 256, 256, 0, stream>>>(
        x, w_qkv, w_proj, xh, wh, wp);
    bias_precompute<<<(NH * 13 * 13 * 256 + 255) / 256, 256, 0, stream>>>(
        table, rel_idx, biasP);

    gemm_qkv_mfma<<<450, 512, 0, stream>>>(xh, wh, qbf, kbf, vbf);
    attn_mfma<<<dim3(NB * NH, 2), 256, 0, stream>>>(qbf, kbf, vbf, biasP, ab);
    gemm_proj_mfma<<<150, 512, 0, stream>>>(ab, wp, b_proj, out);
}

// Round 3
// 290.476 us; speedup vs baseline: 1.0178x; 1.0178x over previous
//
#include <hip/hip_runtime.h>

// Shapes: B=64, N=197, C=768, H=12, hd=64
// qkv GEMM: plain bf16 (K=768), 128^2 tile m97-structure (3 blocks/CU
// co-residency beats the 256^2 deep pipeline at this shape -- measured r2).
// proj GEMM: plain bf16 (K=768), same structure.
// Attention: MFMA flash-lite, bias pre-gathered in fragment layout.
// grid 768x1: one block per (b,h); V-stage paid once, 4 q-tile reps/wave.

#define NB   64
#define NN   197
#define NC   768
#define NH   12
#define HD   64
#define MM   (NB*NN)      // 12608
#define MR   12672        // 99*128
#define NP   208          // 13*16
#define SZQ  ((size_t)NB * NH * NN * HD)

typedef unsigned short ushort_t;
typedef __attribute__((ext_vector_type(8))) short short8;
typedef __attribute__((ext_vector_type(4))) float f32x4;
union U128 { uint4 u; short8 s; };

__device__ __forceinline__ unsigned bf16_rne(float f) {
    unsigned u = __float_as_uint(f);
    return (u + 0x7fffu + ((u >> 16) & 1u)) >> 16;
}

__device__ __forceinline__ void gld16(unsigned short* lds, const unsigned short* g) {
    __builtin_amdgcn_global_load_lds(
        (const __attribute__((address_space(1))) void*)g,
        (__attribute__((address_space(3))) void*)lds, 16, 0, 0);
}

// ---------------------------------------------------------------------------
// Converts: x -> xh, w_qkv -> wh, w_proj -> wp (all bf16 hi, stride NC)
// ---------------------------------------------------------------------------
__global__ __launch_bounds__(256) void convert_all(
    const float* __restrict__ x, const float* __restrict__ w_qkv,
    const float* __restrict__ w_proj,
    ushort_t* __restrict__ xh, ushort_t* __restrict__ wh,
    ushort_t* __restrict__ wp)
{
    int idx = blockIdx.x * 256 + threadIdx.x;
    if (idx >= (MM + 2304 + 768) * 192) return;
    int r = idx / 192;
    int c = (idx - r * 192) * 4;
    const float* src;
    ushort_t* dsth;
    if (r < MM) {
        src = x + (size_t)r * NC; dsth = xh + (size_t)r * NC + c;
    } else if (r < MM + 2304) {
        int rr = r - MM;
        src = w_qkv + (size_t)rr * NC; dsth = wh + (size_t)rr * NC + c;
    } else {
        int rr = r - MM - 2304;
        src = w_proj + (size_t)rr * NC; dsth = wp + (size_t)rr * NC + c;
    }
    float4 f = *(const float4*)(src + c);
    ushort4 hv = { (ushort_t)bf16_rne(f.x), (ushort_t)bf16_rne(f.y),
                   (ushort_t)bf16_rne(f.z), (ushort_t)bf16_rne(f.w) };
    *(ushort4*)dsth = hv;
}

// ---------------------------------------------------------------------------
// biasP in MFMA C-fragment layout: [h][qt][kt][quad][l15][r] f32.
// ---------------------------------------------------------------------------
__global__ __launch_bounds__(256) void bias_precompute(
    const float* __restrict__ table, const int* __restrict__ rel_index,
    float* __restrict__ biasP)
{
    int i = blockIdx.x * 256 + threadIdx.x;
    if (i >= NH * 13 * 13 * 256) return;
    int r = i & 3, l15 = (i >> 2) & 15, quad = (i >> 6) & 3;
    int t = i >> 8;
    int kt = t % 13; int t2 = t / 13;
    int qt = t2 % 13; int h = t2 / 13;
    int n = qt * 16 + quad * 4 + r;
    int m = kt * 16 + l15;
    float v = -1e30f;
    if (n < NN && m < NN) v = table[rel_index[n * NN + m] * NH + h];
    biasP[i] = v;
}

// ---------------------------------------------------------------------------
// bf16 MFMA mainloop; strides + kiters parameterized. 128^2, 4 waves.
// ---------------------------------------------------------------------------
__device__ __forceinline__ void gemm_mainloop(
    const ushort_t* __restrict__ A2, int sA,
    const ushort_t* __restrict__ B2, int sB,
    int m0, int n0, int kiters, ushort_t* Abuf, ushort_t* Bbuf, f32x4 acc[4][4])
{
    const int tid = threadIdx.x;
    const int w = tid >> 6, lane = tid & 63;
    const int wm = w & 1, wn = w >> 1;
    const int lr = lane >> 3, lc = lane & 7;
    const int gch = lc ^ lr;

    const ushort_t* Ag = A2 + (size_t)(m0 + w * 32 + lr) * sA + gch * 8;
    const ushort_t* Bg = B2 + (size_t)(n0 + w * 32 + lr) * sB + gch * 8;
    ushort_t* Al = Abuf + (w * 32) * 64;
    ushort_t* Bl = Bbuf + (w * 32) * 64;

    int aoff[4], boff[4];
    const int quad = lane >> 4, l15 = lane & 15;
    #pragma unroll
    for (int t = 0; t < 4; t++) {
        int ra = wm * 64 + t * 16 + l15;
        aoff[t] = ra * 64 + ((quad ^ (ra & 7)) << 3);
        int rb = wn * 64 + t * 16 + l15;
        boff[t] = rb * 64 + ((quad ^ (rb & 7)) << 3);
    }

    for (int ks = 0; ks < kiters; ks++) {
        __syncthreads();
        #pragma unroll
        for (int it = 0; it < 4; it++) {
            gld16(Al + it * 8 * 64, Ag + (size_t)it * 8 * sA);
            gld16(Bl + it * 8 * 64, Bg + (size_t)it * 8 * sB);
        }
        __syncthreads();
        #pragma unroll
        for (int k0 = 0; k0 < 2; k0++) {
            U128 af[4], bf[4];
            #pragma unroll
            for (int t = 0; t < 4; t++) {
                af[t].u = *(const uint4*)&Abuf[aoff[t] ^ (k0 << 5)];
                bf[t].u = *(const uint4*)&Bbuf[boff[t] ^ (k0 << 5)];
            }
            #pragma unroll
            for (int i = 0; i < 4; i++)
                #pragma unroll
                for (int j = 0; j < 4; j++)
                    acc[i][j] = __builtin_amdgcn_mfma_f32_16x16x32_bf16(
                        af[i].s, bf[j].s, acc[i][j], 0, 0, 0);
        }
        Ag += 64; Bg += 64;
    }
}

// GEMM1: xh[MR,768] * wh[2304,768]^T -> qbf (scaled), kbf, vbf (bf16 [bh][n][d])
// grid (18, 99): n-tiles fastest -> A-slice L2/L3-hot across its 18 consumers.
__global__ __launch_bounds__(256) void gemm_qkv_mfma(
    const ushort_t* __restrict__ A2, const ushort_t* __restrict__ B2,
    ushort_t* __restrict__ qbf, ushort_t* __restrict__ kbf,
    ushort_t* __restrict__ vbf)
{
    __shared__ ushort_t Abuf[128 * 64];
    __shared__ ushort_t Bbuf[128 * 64];
    f32x4 acc[4][4];
    f32x4 z = {0.f, 0.f, 0.f, 0.f};
    #pragma unroll
    for (int i = 0; i < 4; i++)
        #pragma unroll
        for (int j = 0; j < 4; j++) acc[i][j] = z;

    const int m0 = blockIdx.y * 128, n0 = blockIdx.x * 128;
    gemm_mainloop(A2, NC, B2, NC, m0, n0, 12, Abuf, Bbuf, acc);

    const int tid = threadIdx.x;
    const int w = tid >> 6, lane = tid & 63;
    const int wm = w & 1, wn = w >> 1;
    const int quad = lane >> 4, l15 = lane & 15;

    // hoist row decomposition (16 div/mod instead of 64)
    size_t baseo[4][4];
    bool valid[4][4];
    #pragma unroll
    for (int mt = 0; mt < 4; mt++) {
        #pragma unroll
        for (int r = 0; r < 4; r++) {
            int m = m0 + wm * 64 + mt * 16 + quad * 4 + r;
            valid[mt][r] = (m < MM);
            int mc = valid[mt][r] ? m : 0;
            int b_ = mc / NN, n_ = mc - b_ * NN;
            baseo[mt][r] = ((size_t)b_ * NH * NN + n_) * HD;
        }
    }
    #pragma unroll
    for (int nt = 0; nt < 4; nt++) {
        int c0 = n0 + wn * 64 + nt * 16;
        int tq = c0 / NC;
        int wi = c0 - tq * NC;
        int hh = wi >> 6;
        int d0 = (wi & 63) + l15;
        ushort_t* dst = (tq == 0) ? qbf : (tq == 1) ? kbf : vbf;
        float scale = (tq == 0) ? 0.125f : 1.0f;
        size_t hoff = (size_t)hh * (NN * HD) + d0;
        #pragma unroll
        for (int mt = 0; mt < 4; mt++) {
            #pragma unroll
            for (int r = 0; r < 4; r++) {
                if (valid[mt][r])
                    dst[baseo[mt][r] + hoff] = (ushort_t)bf16_rne(acc[mt][nt][r] * scale);
            }
        }
    }
}

// GEMM2: ab[MR,768] * wp[768,768]^T + bias -> out fp32. grid (6,99).
__global__ __launch_bounds__(256) void gemm_proj_mfma(
    const ushort_t* __restrict__ A2, const ushort_t* __restrict__ B2,
    const float* __restrict__ bias, float* __restrict__ out)
{
    __shared__ ushort_t Abuf[128 * 64];
    __shared__ ushort_t Bbuf[128 * 64];
    f32x4 acc[4][4];
    f32x4 z = {0.f, 0.f, 0.f, 0.f};
    #pragma unroll
    for (int i = 0; i < 4; i++)
        #pragma unroll
        for (int j = 0; j < 4; j++) acc[i][j] = z;

    const int m0 = blockIdx.y * 128, n0 = blockIdx.x * 128;
    gemm_mainloop(A2, NC, B2, NC, m0, n0, 12, Abuf, Bbuf, acc);

    const int tid = threadIdx.x;
    const int w = tid >> 6, lane = tid & 63;
    const int wm = w & 1, wn = w >> 1;
    const int quad = lane >> 4, l15 = lane & 15;
    #pragma unroll
    for (int nt = 0; nt < 4; nt++) {
        int col = n0 + wn * 64 + nt * 16 + l15;
        float bi = bias[col];
        #pragma unroll
        for (int mt = 0; mt < 4; mt++) {
            #pragma unroll
            for (int r = 0; r < 4; r++) {
                int m = m0 + wm * 64 + mt * 16 + quad * 4 + r;
                if (m < MM)
                    out[(size_t)m * NC + col] = acc[mt][nt][r] + bi;
            }
        }
    }
}

// ---------------------------------------------------------------------------
// MFMA attention. grid 768 x 256 threads (4 waves). One block per (b,h):
// V-stage paid once; each wave handles up to 4 q-tiles (13 tiles over 4
// waves: {4,3,3,3}).
// ---------------------------------------------------------------------------
__global__ __launch_bounds__(256) void attn_mfma(
    const ushort_t* __restrict__ qbf, const ushort_t* __restrict__ kbf,
    const ushort_t* __restrict__ vbf, const float* __restrict__ biasP,
    ushort_t* __restrict__ ab)
{
    __shared__ ushort_t Vt[64 * 232];        // Vt[d][key], 29696 B
    __shared__ ushort_t Pl[4][16 * 232];     // per-wave P / V-stage / O-transpose

    const int bh = blockIdx.x;
    const int b = bh / NH, h = bh % NH;
    const int tid = threadIdx.x;
    const int w = tid >> 6, lane = tid & 63;
    const int quad = lane >> 4, l15 = lane & 15;
    const size_t base = (size_t)bh * (NN * HD);
    const ushort_t* kg = kbf + base;
    const ushort_t* vg = vbf + base;
    const ushort_t* qg = qbf + base;

    // stage V row-major coalesced, then LDS->LDS transpose into Vt
    ushort_t* Vstage = &Pl[0][0];            // 208*64 = 13312 <= 14848
    for (int idx = tid; idx < NP * 8; idx += 256) {
        int row = idx >> 3, ch = idx & 7;
        uint4 val = {0u, 0u, 0u, 0u};
        if (row < NN) val = *(const uint4*)(vg + (size_t)row * HD + ch * 8);
        *(uint4*)&Vstage[row * HD + ch * 8] = val;
    }
    __syncthreads();
    for (int task = tid; task < 64 * 29; task += 256) {
        int d = task & 63, kc = task >> 6;
        ushort_t tmp[8];
        #pragma unroll
        for (int j = 0; j < 8; j++) {
            int key = kc * 8 + j;
            tmp[j] = (key < NP) ? Vstage[key * HD + d] : (ushort_t)0;
        }
        uint4 u;
        u.x = (unsigned)tmp[0] | ((unsigned)tmp[1] << 16);
        u.y = (unsigned)tmp[2] | ((unsigned)tmp[3] << 16);
        u.z = (unsigned)tmp[4] | ((unsigned)tmp[5] << 16);
        u.w = (unsigned)tmp[6] | ((unsigned)tmp[7] << 16);
        *(uint4*)&Vt[d * 232 + kc * 8] = u;
    }
    __syncthreads();                         // Vt ready; Pl free

    #pragma unroll
    for (int rep = 0; rep < 4; rep++) {
        int qt = w + rep * 4;
        if (qt > 12) break;
        const int q0 = qt * 16;

        int qrow = q0 + l15; if (qrow > NN - 1) qrow = NN - 1;
        U128 qf0, qf1;
        qf0.u = *(const uint4*)(qg + (size_t)qrow * HD + quad * 8);
        qf1.u = *(const uint4*)(qg + (size_t)qrow * HD + 32 + quad * 8);

        // S init from biasP: one coalesced float4 per kt
        f32x4 S[13];
        const float* bp = biasP + ((size_t)(h * 13 + qt) * 13) * 256 + (quad << 6) + (l15 << 2);
        #pragma unroll
        for (int kt = 0; kt < 13; kt++) {
            float4 bv = *(const float4*)(bp + kt * 256);
            S[kt][0] = bv.x; S[kt][1] = bv.y; S[kt][2] = bv.z; S[kt][3] = bv.w;
        }

        // QK^T: 2 MFMAs per kt (Q plain bf16)
        #pragma unroll
        for (int kt = 0; kt < 13; kt++) {
            int krow = kt * 16 + l15; if (krow > NN - 1) krow = NN - 1;
            U128 k0, k1;
            k0.u = *(const uint4*)(kg + (size_t)krow * HD + quad * 8);
            k1.u = *(const uint4*)(kg + (size_t)krow * HD + 32 + quad * 8);
            S[kt] = __builtin_amdgcn_mfma_f32_16x16x32_bf16(qf0.s, k0.s, S[kt], 0, 0, 0);
            S[kt] = __builtin_amdgcn_mfma_f32_16x16x32_bf16(qf1.s, k1.s, S[kt], 0, 0, 0);
        }

        // softmax (rows quad*4+r over 16 l15 lanes x 13 tiles)
        ushort_t* P = Pl[w];
        #pragma unroll
        for (int r = 0; r < 4; r++) {
            float mx = S[0][r];
            #pragma unroll
            for (int kt = 1; kt < 13; kt++) mx = fmaxf(mx, S[kt][r]);
            mx = fmaxf(mx, __shfl_xor(mx, 1));
            mx = fmaxf(mx, __shfl_xor(mx, 2));
            mx = fmaxf(mx, __shfl_xor(mx, 4));
            mx = fmaxf(mx, __shfl_xor(mx, 8));
            float sum = 0.f;
            #pragma unroll
            for (int kt = 0; kt < 13; kt++) {
                float e = __expf(S[kt][r] - mx);
                S[kt][r] = e;
                sum += e;
            }
            sum += __shfl_xor(sum, 1);
            sum += __shfl_xor(sum, 2);
            sum += __shfl_xor(sum, 4);
            sum += __shfl_xor(sum, 8);
            float inv = 1.0f / sum;
            int prow = quad * 4 + r;
            #pragma unroll
            for (int kt = 0; kt < 13; kt++)
                P[prow * 232 + kt * 16 + l15] = (ushort_t)bf16_rne(S[kt][r] * inv);
        }
        // zero P keys 208..231
        #pragma unroll
        for (int z = 0; z < 3; z++) {
            int idx = z * 64 + lane;
            int row = idx / 12, c = idx - row * 12;
            *(unsigned*)&P[row * 232 + NP + 2 * c] = 0u;
        }

        // PV
        f32x4 O[4];
        f32x4 z4 = {0.f, 0.f, 0.f, 0.f};
        #pragma unroll
        for (int dt = 0; dt < 4; dt++) O[dt] = z4;
        #pragma unroll
        for (int ks = 0; ks < 7; ks++) {
            U128 pf;
            pf.u = *(const uint4*)&P[l15 * 232 + ks * 32 + quad * 8];
            #pragma unroll
            for (int dt = 0; dt < 4; dt++) {
                U128 vf;
                vf.u = *(const uint4*)&Vt[(dt * 16 + l15) * 232 + ks * 32 + quad * 8];
                O[dt] = __builtin_amdgcn_mfma_f32_16x16x32_bf16(pf.s, vf.s, O[dt], 0, 0, 0);
            }
        }

        // epilogue: transpose O through wave-private LDS, emit b128 bf16 hi
        float* Osh = (float*)&Pl[w][0];      // stride 68 floats (16B-aligned rows)
        #pragma unroll
        for (int dt = 0; dt < 4; dt++)
            #pragma unroll
            for (int r = 0; r < 4; r++)
                Osh[(quad * 4 + r) * 68 + dt * 16 + l15] = O[dt][r];
        int orow = lane >> 2;
        int d0 = (lane & 3) << 4;
        int q = q0 + orow;
        if (q < NN) {
            unsigned hiw[8];
            #pragma unroll
            for (int k4 = 0; k4 < 4; k4++) {
                float4 f = *(const float4*)&Osh[orow * 68 + d0 + k4 * 4];
                unsigned h0 = bf16_rne(f.x), h1 = bf16_rne(f.y);
                unsigned h2 = bf16_rne(f.z), h3 = bf16_rne(f.w);
                hiw[k4 * 2]     = h0 | (h1 << 16);
                hiw[k4 * 2 + 1] = h2 | (h3 << 16);
            }
            size_t baseo = ((size_t)b * NN + q) * NC + h * HD + d0;
            uint4 hA = {hiw[0], hiw[1], hiw[2], hiw[3]};
            uint4 hB = {hiw[4], hiw[5], hiw[6], hiw[7]};
            *(uint4*)&ab[baseo] = hA;
            *(uint4*)&ab[baseo + 8] = hB;
        }
    }
}

// ---------------------------------------------------------------------------
extern "C" void kernel_launch(void* const* d_in, const int* in_sizes, int n_in,
                              void* d_out, int out_size, void* d_ws, size_t ws_size,
                              hipStream_t stream)
{
    const float* x        = (const float*)d_in[0];
    const float* table    = (const float*)d_in[1];
    const float* w_qkv    = (const float*)d_in[2];
    const float* w_proj   = (const float*)d_in[3];
    const float* b_proj   = (const float*)d_in[4];
    const int*   rel_idx  = (const int*)d_in[5];
    float* out = (float*)d_out;

    ushort_t* xh  = (ushort_t*)d_ws;                        // MR*768
    ushort_t* wh  = xh + (size_t)MR * NC;                   // 2304*768
    ushort_t* wp  = wh + (size_t)2304 * NC;                 // 768*768
    ushort_t* ab  = wp + (size_t)768 * NC;                  // MR*768
    ushort_t* qbf = ab + (size_t)MR * NC;                   // SZQ each
    ushort_t* kbf = qbf + SZQ;
    ushort_t* vbf = kbf + SZQ;
    float* biasP  = (float*)(vbf + SZQ);                    // 12*13*13*256 f32

    const int cvt_quads = (MM + 2304 + 768) * 192;
    convert_all<<<(cvt_quads + 255) / 256, 256, 0, stream>>>(
        x, w_qkv, w_proj, xh, wh, wp);
    bias_precompute<<<(NH * 13 * 13 * 256 + 255) / 256, 256, 0, stream>>>(
        table, rel_idx, biasP);

    gemm_qkv_mfma<<<dim3(18, 99), 256, 0, stream>>>(xh, wh, qbf, kbf, vbf);
    attn_mfma<<<768, 256, 0, stream>>>(qbf, kbf, vbf, biasP, ab);
    gemm_proj_mfma<<<dim3(6, 99), 256, 0, stream>>>(ab, wp, b_proj, out);
}

// Round 4
// 280.238 us; speedup vs baseline: 1.0550x; 1.0365x over previous
//
#include <hip/hip_runtime.h>

// Shapes: B=64, N=197, C=768, H=12, hd=64
// qkv/proj GEMM: plain bf16 (K=768), 128^2 m97-structure (3 blocks/CU).
// Attention: MFMA flash-lite, bias pre-gathered in fragment layout.
// grid 768x1, one block per (b,h). LDS strides 208 (not 232): total
// 53248 B -> 3 blocks/CU so ALL 768 blocks co-resident in one round
// (was 59392 B -> 2/CU -> 1.5 rounds, occupancy 13.9%). PV tail chunk
// masks P for keys>=208 instead of relying on zero-padded LDS columns.

#define NB   64
#define NN   197
#define NC   768
#define NH   12
#define HD   64
#define MM   (NB*NN)      // 12608
#define MR   12672        // 99*128
#define NP   208          // 13*16
#define WV   208          // LDS row stride (ushorts); 416B = 26*16 aligned
#define SZQ  ((size_t)NB * NH * NN * HD)

typedef unsigned short ushort_t;
typedef __attribute__((ext_vector_type(8))) short short8;
typedef __attribute__((ext_vector_type(4))) float f32x4;
union U128 { uint4 u; short8 s; };

__device__ __forceinline__ unsigned bf16_rne(float f) {
    unsigned u = __float_as_uint(f);
    return (u + 0x7fffu + ((u >> 16) & 1u)) >> 16;
}

__device__ __forceinline__ void gld16(unsigned short* lds, const unsigned short* g) {
    __builtin_amdgcn_global_load_lds(
        (const __attribute__((address_space(1))) void*)g,
        (__attribute__((address_space(3))) void*)lds, 16, 0, 0);
}

// ---------------------------------------------------------------------------
// Converts: x -> xh, w_qkv -> wh, w_proj -> wp (all bf16 hi, stride NC)
// ---------------------------------------------------------------------------
__global__ __launch_bounds__(256) void convert_all(
    const float* __restrict__ x, const float* __restrict__ w_qkv,
    const float* __restrict__ w_proj,
    ushort_t* __restrict__ xh, ushort_t* __restrict__ wh,
    ushort_t* __restrict__ wp)
{
    int idx = blockIdx.x * 256 + threadIdx.x;
    if (idx >= (MM + 2304 + 768) * 192) return;
    int r = idx / 192;
    int c = (idx - r * 192) * 4;
    const float* src;
    ushort_t* dsth;
    if (r < MM) {
        src = x + (size_t)r * NC; dsth = xh + (size_t)r * NC + c;
    } else if (r < MM + 2304) {
        int rr = r - MM;
        src = w_qkv + (size_t)rr * NC; dsth = wh + (size_t)rr * NC + c;
    } else {
        int rr = r - MM - 2304;
        src = w_proj + (size_t)rr * NC; dsth = wp + (size_t)rr * NC + c;
    }
    float4 f = *(const float4*)(src + c);
    ushort4 hv = { (ushort_t)bf16_rne(f.x), (ushort_t)bf16_rne(f.y),
                   (ushort_t)bf16_rne(f.z), (ushort_t)bf16_rne(f.w) };
    *(ushort4*)dsth = hv;
}

// ---------------------------------------------------------------------------
// biasP in MFMA C-fragment layout: [h][qt][kt][quad][l15][r] f32.
// ---------------------------------------------------------------------------
__global__ __launch_bounds__(256) void bias_precompute(
    const float* __restrict__ table, const int* __restrict__ rel_index,
    float* __restrict__ biasP)
{
    int i = blockIdx.x * 256 + threadIdx.x;
    if (i >= NH * 13 * 13 * 256) return;
    int r = i & 3, l15 = (i >> 2) & 15, quad = (i >> 6) & 3;
    int t = i >> 8;
    int kt = t % 13; int t2 = t / 13;
    int qt = t2 % 13; int h = t2 / 13;
    int n = qt * 16 + quad * 4 + r;
    int m = kt * 16 + l15;
    float v = -1e30f;
    if (n < NN && m < NN) v = table[rel_index[n * NN + m] * NH + h];
    biasP[i] = v;
}

// ---------------------------------------------------------------------------
// bf16 MFMA mainloop; strides + kiters parameterized. 128^2, 4 waves.
// ---------------------------------------------------------------------------
__device__ __forceinline__ void gemm_mainloop(
    const ushort_t* __restrict__ A2, int sA,
    const ushort_t* __restrict__ B2, int sB,
    int m0, int n0, int kiters, ushort_t* Abuf, ushort_t* Bbuf, f32x4 acc[4][4])
{
    const int tid = threadIdx.x;
    const int w = tid >> 6, lane = tid & 63;
    const int wm = w & 1, wn = w >> 1;
    const int lr = lane >> 3, lc = lane & 7;
    const int gch = lc ^ lr;

    const ushort_t* Ag = A2 + (size_t)(m0 + w * 32 + lr) * sA + gch * 8;
    const ushort_t* Bg = B2 + (size_t)(n0 + w * 32 + lr) * sB + gch * 8;
    ushort_t* Al = Abuf + (w * 32) * 64;
    ushort_t* Bl = Bbuf + (w * 32) * 64;

    int aoff[4], boff[4];
    const int quad = lane >> 4, l15 = lane & 15;
    #pragma unroll
    for (int t = 0; t < 4; t++) {
        int ra = wm * 64 + t * 16 + l15;
        aoff[t] = ra * 64 + ((quad ^ (ra & 7)) << 3);
        int rb = wn * 64 + t * 16 + l15;
        boff[t] = rb * 64 + ((quad ^ (rb & 7)) << 3);
    }

    for (int ks = 0; ks < kiters; ks++) {
        __syncthreads();
        #pragma unroll
        for (int it = 0; it < 4; it++) {
            gld16(Al + it * 8 * 64, Ag + (size_t)it * 8 * sA);
            gld16(Bl + it * 8 * 64, Bg + (size_t)it * 8 * sB);
        }
        __syncthreads();
        #pragma unroll
        for (int k0 = 0; k0 < 2; k0++) {
            U128 af[4], bf[4];
            #pragma unroll
            for (int t = 0; t < 4; t++) {
                af[t].u = *(const uint4*)&Abuf[aoff[t] ^ (k0 << 5)];
                bf[t].u = *(const uint4*)&Bbuf[boff[t] ^ (k0 << 5)];
            }
            #pragma unroll
            for (int i = 0; i < 4; i++)
                #pragma unroll
                for (int j = 0; j < 4; j++)
                    acc[i][j] = __builtin_amdgcn_mfma_f32_16x16x32_bf16(
                        af[i].s, bf[j].s, acc[i][j], 0, 0, 0);
        }
        Ag += 64; Bg += 64;
    }
}

// GEMM1: xh[MR,768] * wh[2304,768]^T -> qbf (scaled), kbf, vbf (bf16 [bh][n][d])
__global__ __launch_bounds__(256) void gemm_qkv_mfma(
    const ushort_t* __restrict__ A2, const ushort_t* __restrict__ B2,
    ushort_t* __restrict__ qbf, ushort_t* __restrict__ kbf,
    ushort_t* __restrict__ vbf)
{
    __shared__ ushort_t Abuf[128 * 64];
    __shared__ ushort_t Bbuf[128 * 64];
    f32x4 acc[4][4];
    f32x4 z = {0.f, 0.f, 0.f, 0.f};
    #pragma unroll
    for (int i = 0; i < 4; i++)
        #pragma unroll
        for (int j = 0; j < 4; j++) acc[i][j] = z;

    const int m0 = blockIdx.y * 128, n0 = blockIdx.x * 128;
    gemm_mainloop(A2, NC, B2, NC, m0, n0, 12, Abuf, Bbuf, acc);

    const int tid = threadIdx.x;
    const int w = tid >> 6, lane = tid & 63;
    const int wm = w & 1, wn = w >> 1;
    const int quad = lane >> 4, l15 = lane & 15;

    size_t baseo[4][4];
    bool valid[4][4];
    #pragma unroll
    for (int mt = 0; mt < 4; mt++) {
        #pragma unroll
        for (int r = 0; r < 4; r++) {
            int m = m0 + wm * 64 + mt * 16 + quad * 4 + r;
            valid[mt][r] = (m < MM);
            int mc = valid[mt][r] ? m : 0;
            int b_ = mc / NN, n_ = mc - b_ * NN;
            baseo[mt][r] = ((size_t)b_ * NH * NN + n_) * HD;
        }
    }
    #pragma unroll
    for (int nt = 0; nt < 4; nt++) {
        int c0 = n0 + wn * 64 + nt * 16;
        int tq = c0 / NC;
        int wi = c0 - tq * NC;
        int hh = wi >> 6;
        int d0 = (wi & 63) + l15;
        ushort_t* dst = (tq == 0) ? qbf : (tq == 1) ? kbf : vbf;
        float scale = (tq == 0) ? 0.125f : 1.0f;
        size_t hoff = (size_t)hh * (NN * HD) + d0;
        #pragma unroll
        for (int mt = 0; mt < 4; mt++) {
            #pragma unroll
            for (int r = 0; r < 4; r++) {
                if (valid[mt][r])
                    dst[baseo[mt][r] + hoff] = (ushort_t)bf16_rne(acc[mt][nt][r] * scale);
            }
        }
    }
}

// GEMM2: ab[MR,768] * wp[768,768]^T + bias -> out fp32. grid (6,99).
__global__ __launch_bounds__(256) void gemm_proj_mfma(
    const ushort_t* __restrict__ A2, const ushort_t* __restrict__ B2,
    const float* __restrict__ bias, float* __restrict__ out)
{
    __shared__ ushort_t Abuf[128 * 64];
    __shared__ ushort_t Bbuf[128 * 64];
    f32x4 acc[4][4];
    f32x4 z = {0.f, 0.f, 0.f, 0.f};
    #pragma unroll
    for (int i = 0; i < 4; i++)
        #pragma unroll
        for (int j = 0; j < 4; j++) acc[i][j] = z;

    const int m0 = blockIdx.y * 128, n0 = blockIdx.x * 128;
    gemm_mainloop(A2, NC, B2, NC, m0, n0, 12, Abuf, Bbuf, acc);

    const int tid = threadIdx.x;
    const int w = tid >> 6, lane = tid & 63;
    const int wm = w & 1, wn = w >> 1;
    const int quad = lane >> 4, l15 = lane & 15;
    #pragma unroll
    for (int nt = 0; nt < 4; nt++) {
        int col = n0 + wn * 64 + nt * 16 + l15;
        float bi = bias[col];
        #pragma unroll
        for (int mt = 0; mt < 4; mt++) {
            #pragma unroll
            for (int r = 0; r < 4; r++) {
                int m = m0 + wm * 64 + mt * 16 + quad * 4 + r;
                if (m < MM)
                    out[(size_t)m * NC + col] = acc[mt][nt][r] + bi;
            }
        }
    }
}

// ---------------------------------------------------------------------------
// MFMA attention. grid 768 x 256 threads (4 waves). One block per (b,h).
// LDS 53248 B -> 3 blocks/CU, all 768 blocks co-resident in one round.
// ---------------------------------------------------------------------------
__global__ __launch_bounds__(256) void attn_mfma(
    const ushort_t* __restrict__ qbf, const ushort_t* __restrict__ kbf,
    const ushort_t* __restrict__ vbf, const float* __restrict__ biasP,
    ushort_t* __restrict__ ab)
{
    __shared__ ushort_t Vt[64 * WV];         // Vt[d][key], 26624 B
    __shared__ ushort_t Pl[4][16 * WV];      // per-wave P / V-stage / O-transpose

    const int bh = blockIdx.x;
    const int b = bh / NH, h = bh % NH;
    const int tid = threadIdx.x;
    const int w = tid >> 6, lane = tid & 63;
    const int quad = lane >> 4, l15 = lane & 15;
    const size_t base = (size_t)bh * (NN * HD);
    const ushort_t* kg = kbf + base;
    const ushort_t* vg = vbf + base;
    const ushort_t* qg = qbf + base;

    // stage V row-major coalesced, then LDS->LDS transpose into Vt
    ushort_t* Vstage = &Pl[0][0];            // 208*64 = 13312 = 4*16*208 exactly
    for (int idx = tid; idx < NP * 8; idx += 256) {
        int row = idx >> 3, ch = idx & 7;
        uint4 val = {0u, 0u, 0u, 0u};
        if (row < NN) val = *(const uint4*)(vg + (size_t)row * HD + ch * 8);
        *(uint4*)&Vstage[row * HD + ch * 8] = val;
    }
    __syncthreads();
    for (int task = tid; task < 64 * 26; task += 256) {
        int d = task & 63, kc = task >> 6;   // kc 0..25, keys kc*8..kc*8+7 < 208
        ushort_t tmp[8];
        #pragma unroll
        for (int j = 0; j < 8; j++)
            tmp[j] = Vstage[(kc * 8 + j) * HD + d];
        uint4 u;
        u.x = (unsigned)tmp[0] | ((unsigned)tmp[1] << 16);
        u.y = (unsigned)tmp[2] | ((unsigned)tmp[3] << 16);
        u.z = (unsigned)tmp[4] | ((unsigned)tmp[5] << 16);
        u.w = (unsigned)tmp[6] | ((unsigned)tmp[7] << 16);
        *(uint4*)&Vt[d * WV + kc * 8] = u;
    }
    __syncthreads();                         // Vt ready; Pl free

    #pragma unroll
    for (int rep = 0; rep < 4; rep++) {
        int qt = w + rep * 4;
        if (qt > 12) break;
        const int q0 = qt * 16;

        int qrow = q0 + l15; if (qrow > NN - 1) qrow = NN - 1;
        U128 qf0, qf1;
        qf0.u = *(const uint4*)(qg + (size_t)qrow * HD + quad * 8);
        qf1.u = *(const uint4*)(qg + (size_t)qrow * HD + 32 + quad * 8);

        // S init from biasP: one coalesced float4 per kt
        f32x4 S[13];
        const float* bp = biasP + ((size_t)(h * 13 + qt) * 13) * 256 + (quad << 6) + (l15 << 2);
        #pragma unroll
        for (int kt = 0; kt < 13; kt++) {
            float4 bv = *(const float4*)(bp + kt * 256);
            S[kt][0] = bv.x; S[kt][1] = bv.y; S[kt][2] = bv.z; S[kt][3] = bv.w;
        }

        // QK^T: 2 MFMAs per kt (Q plain bf16)
        #pragma unroll
        for (int kt = 0; kt < 13; kt++) {
            int krow = kt * 16 + l15; if (krow > NN - 1) krow = NN - 1;
            U128 k0, k1;
            k0.u = *(const uint4*)(kg + (size_t)krow * HD + quad * 8);
            k1.u = *(const uint4*)(kg + (size_t)krow * HD + 32 + quad * 8);
            S[kt] = __builtin_amdgcn_mfma_f32_16x16x32_bf16(qf0.s, k0.s, S[kt], 0, 0, 0);
            S[kt] = __builtin_amdgcn_mfma_f32_16x16x32_bf16(qf1.s, k1.s, S[kt], 0, 0, 0);
        }

        // softmax (rows quad*4+r over 16 l15 lanes x 13 tiles)
        ushort_t* P = Pl[w];
        #pragma unroll
        for (int r = 0; r < 4; r++) {
            float mx = S[0][r];
            #pragma unroll
            for (int kt = 1; kt < 13; kt++) mx = fmaxf(mx, S[kt][r]);
            mx = fmaxf(mx, __shfl_xor(mx, 1));
            mx = fmaxf(mx, __shfl_xor(mx, 2));
            mx = fmaxf(mx, __shfl_xor(mx, 4));
            mx = fmaxf(mx, __shfl_xor(mx, 8));
            float sum = 0.f;
            #pragma unroll
            for (int kt = 0; kt < 13; kt++) {
                float e = __expf(S[kt][r] - mx);
                S[kt][r] = e;
                sum += e;
            }
            sum += __shfl_xor(sum, 1);
            sum += __shfl_xor(sum, 2);
            sum += __shfl_xor(sum, 4);
            sum += __shfl_xor(sum, 8);
            float inv = 1.0f / sum;
            int prow = quad * 4 + r;
            #pragma unroll
            for (int kt = 0; kt < 13; kt++)
                P[prow * WV + kt * 16 + l15] = (ushort_t)bf16_rne(S[kt][r] * inv);
        }
        // NOTE: no zero-pad of P cols 208+ -- the ks==6 PV chunk masks instead.

        // PV: 7 chunks of 32 keys; chunk 6 covers keys 192..223, of which
        // 208..223 (quads 2,3) are masked to pf=0 (their P was exact 0 before).
        f32x4 O[4];
        f32x4 z4 = {0.f, 0.f, 0.f, 0.f};
        #pragma unroll
        for (int dt = 0; dt < 4; dt++) O[dt] = z4;
        #pragma unroll
        for (int ks = 0; ks < 7; ks++) {
            int pc = ks * 32 + quad * 8;
            bool vld = (pc < NP);            // false only for ks==6, quad>=2
            int pcc = vld ? pc : 0;          // clamped in-bounds address
            U128 pf;
            pf.u = *(const uint4*)&P[l15 * WV + pcc];
            if (!vld) { pf.u.x = 0u; pf.u.y = 0u; pf.u.z = 0u; pf.u.w = 0u; }
            #pragma unroll
            for (int dt = 0; dt < 4; dt++) {
                U128 vf;
                vf.u = *(const uint4*)&Vt[(dt * 16 + l15) * WV + pcc];
                O[dt] = __builtin_amdgcn_mfma_f32_16x16x32_bf16(pf.s, vf.s, O[dt], 0, 0, 0);
            }
        }

        // epilogue: transpose O through wave-private LDS, emit b128 bf16 hi
        float* Osh = (float*)&Pl[w][0];      // stride 68 floats (16B-aligned rows)
        #pragma unroll
        for (int dt = 0; dt < 4; dt++)
            #pragma unroll
            for (int r = 0; r < 4; r++)
                Osh[(quad * 4 + r) * 68 + dt * 16 + l15] = O[dt][r];
        int orow = lane >> 2;
        int d0 = (lane & 3) << 4;
        int q = q0 + orow;
        if (q < NN) {
            unsigned hiw[8];
            #pragma unroll
            for (int k4 = 0; k4 < 4; k4++) {
                float4 f = *(const float4*)&Osh[orow * 68 + d0 + k4 * 4];
                unsigned h0 = bf16_rne(f.x), h1 = bf16_rne(f.y);
                unsigned h2 = bf16_rne(f.z), h3 = bf16_rne(f.w);
                hiw[k4 * 2]     = h0 | (h1 << 16);
                hiw[k4 * 2 + 1] = h2 | (h3 << 16);
            }
            size_t baseo = ((size_t)b * NN + q) * NC + h * HD + d0;
            uint4 hA = {hiw[0], hiw[1], hiw[2], hiw[3]};
            uint4 hB = {hiw[4], hiw[5], hiw[6], hiw[7]};
            *(uint4*)&ab[baseo] = hA;
            *(uint4*)&ab[baseo + 8] = hB;
        }
    }
}

// ---------------------------------------------------------------------------
extern "C" void kernel_launch(void* const* d_in, const int* in_sizes, int n_in,
                              void* d_out, int out_size, void* d_ws, size_t ws_size,
                              hipStream_t stream)
{
    const float* x        = (const float*)d_in[0];
    const float* table    = (const float*)d_in[1];
    const float* w_qkv    = (const float*)d_in[2];
    const float* w_proj   = (const float*)d_in[3];
    const float* b_proj   = (const float*)d_in[4];
    const int*   rel_idx  = (const int*)d_in[5];
    float* out = (float*)d_out;

    ushort_t* xh  = (ushort_t*)d_ws;                        // MR*768
    ushort_t* wh  = xh + (size_t)MR * NC;                   // 2304*768
    ushort_t* wp  = wh + (size_t)2304 * NC;                 // 768*768
    ushort_t* ab  = wp + (size_t)768 * NC;                  // MR*768
    ushort_t* qbf = ab + (size_t)MR * NC;                   // SZQ each
    ushort_t* kbf = qbf + SZQ;
    ushort_t* vbf = kbf + SZQ;
    float* biasP  = (float*)(vbf + SZQ);                    // 12*13*13*256 f32

    const int cvt_quads = (MM + 2304 + 768) * 192;
    convert_all<<<(cvt_quads + 255) / 256, 256, 0, stream>>>(
        x, w_qkv, w_proj, xh, wh, wp);
    bias_precompute<<<(NH * 13 * 13 * 256 + 255) / 256, 256, 0, stream>>>(
        table, rel_idx, biasP);

    gemm_qkv_mfma<<<dim3(18, 99), 256, 0, stream>>>(xh, wh, qbf, kbf, vbf);
    attn_mfma<<<768, 256, 0, stream>>>(qbf, kbf, vbf, biasP, ab);
    gemm_proj_mfma<<<dim3(6, 99), 256, 0, stream>>>(ab, wp, b_proj, out);
}

// Round 5
// 279.864 us; speedup vs baseline: 1.0564x; 1.0013x over previous
//
#include <hip/hip_runtime.h>

// Shapes: B=64, N=197, C=768, H=12, hd=64
// qkv/proj GEMM: plain bf16 (K=768), 128^2 m97-structure (3 blocks/CU),
//   XCD-chunked bijective block swizzle (per-XCD L2 holds A-chunk + full B),
//   qkv epilogue via per-wave LDS transpose -> coalesced uint4 stores.
// Attention: MFMA flash-lite, 3 blocks/CU; K-fragments batch-loaded into
//   registers (13 at a time, statically indexed) so global-load latency is
//   exposed once per half instead of per-kt. launch_bounds(256,3).
// prepare = fused convert + bias gather (one launch fewer).

#define NB   64
#define NN   197
#define NC   768
#define NH   12
#define HD   64
#define MM   (NB*NN)      // 12608
#define MR   12672        // 99*128
#define NP   208          // 13*16
#define PS   208          // P row stride (ushorts)
#define VTS  216          // Vt row stride (ushorts): 432B -> 8-bank spread
#define SZQ  ((size_t)NB * NH * NN * HD)
#define CVTQ ((MM + 2304 + 768) * 192)
#define BIASN (NH * 13 * 13 * 256)

typedef unsigned short ushort_t;
typedef __attribute__((ext_vector_type(8))) short short8;
typedef __attribute__((ext_vector_type(4))) float f32x4;
union U128 { uint4 u; short8 s; };

__device__ __forceinline__ unsigned bf16_rne(float f) {
    unsigned u = __float_as_uint(f);
    return (u + 0x7fffu + ((u >> 16) & 1u)) >> 16;
}

__device__ __forceinline__ void gld16(unsigned short* lds, const unsigned short* g) {
    __builtin_amdgcn_global_load_lds(
        (const __attribute__((address_space(1))) void*)g,
        (__attribute__((address_space(3))) void*)lds, 16, 0, 0);
}

// ---------------------------------------------------------------------------
// prepare: x->xh, w_qkv->wh, w_proj->wp (bf16) AND biasP fragment gather.
// ---------------------------------------------------------------------------
__global__ __launch_bounds__(256) void prepare(
    const float* __restrict__ x, const float* __restrict__ w_qkv,
    const float* __restrict__ w_proj, const float* __restrict__ table,
    const int* __restrict__ rel_index,
    ushort_t* __restrict__ xh, ushort_t* __restrict__ wh,
    ushort_t* __restrict__ wp, float* __restrict__ biasP)
{
    int idx = blockIdx.x * 256 + threadIdx.x;
    if (idx < CVTQ) {
        int r = idx / 192;
        int c = (idx - r * 192) * 4;
        const float* src;
        ushort_t* dsth;
        if (r < MM) {
            src = x + (size_t)r * NC; dsth = xh + (size_t)r * NC + c;
        } else if (r < MM + 2304) {
            int rr = r - MM;
            src = w_qkv + (size_t)rr * NC; dsth = wh + (size_t)rr * NC + c;
        } else {
            int rr = r - MM - 2304;
            src = w_proj + (size_t)rr * NC; dsth = wp + (size_t)rr * NC + c;
        }
        float4 f = *(const float4*)(src + c);
        ushort4 hv = { (ushort_t)bf16_rne(f.x), (ushort_t)bf16_rne(f.y),
                       (ushort_t)bf16_rne(f.z), (ushort_t)bf16_rne(f.w) };
        *(ushort4*)dsth = hv;
    } else {
        int i = idx - CVTQ;
        if (i < BIASN) {
            int r = i & 3, l15 = (i >> 2) & 15, quad = (i >> 6) & 3;
            int t = i >> 8;
            int kt = t % 13; int t2 = t / 13;
            int qt = t2 % 13; int h = t2 / 13;
            int n = qt * 16 + quad * 4 + r;
            int m = kt * 16 + l15;
            float v = -1e30f;
            if (n < NN && m < NN) v = table[rel_index[n * NN + m] * NH + h];
            biasP[i] = v;
        }
    }
}

// ---------------------------------------------------------------------------
// bf16 MFMA mainloop; strides + kiters parameterized. 128^2, 4 waves.
// ---------------------------------------------------------------------------
__device__ __forceinline__ void gemm_mainloop(
    const ushort_t* __restrict__ A2, int sA,
    const ushort_t* __restrict__ B2, int sB,
    int m0, int n0, int kiters, ushort_t* Abuf, ushort_t* Bbuf, f32x4 acc[4][4])
{
    const int tid = threadIdx.x;
    const int w = tid >> 6, lane = tid & 63;
    const int wm = w & 1, wn = w >> 1;
    const int lr = lane >> 3, lc = lane & 7;
    const int gch = lc ^ lr;

    const ushort_t* Ag = A2 + (size_t)(m0 + w * 32 + lr) * sA + gch * 8;
    const ushort_t* Bg = B2 + (size_t)(n0 + w * 32 + lr) * sB + gch * 8;
    ushort_t* Al = Abuf + (w * 32) * 64;
    ushort_t* Bl = Bbuf + (w * 32) * 64;

    int aoff[4], boff[4];
    const int quad = lane >> 4, l15 = lane & 15;
    #pragma unroll
    for (int t = 0; t < 4; t++) {
        int ra = wm * 64 + t * 16 + l15;
        aoff[t] = ra * 64 + ((quad ^ (ra & 7)) << 3);
        int rb = wn * 64 + t * 16 + l15;
        boff[t] = rb * 64 + ((quad ^ (rb & 7)) << 3);
    }

    for (int ks = 0; ks < kiters; ks++) {
        __syncthreads();
        #pragma unroll
        for (int it = 0; it < 4; it++) {
            gld16(Al + it * 8 * 64, Ag + (size_t)it * 8 * sA);
            gld16(Bl + it * 8 * 64, Bg + (size_t)it * 8 * sB);
        }
        __syncthreads();
        #pragma unroll
        for (int k0 = 0; k0 < 2; k0++) {
            U128 af[4], bf[4];
            #pragma unroll
            for (int t = 0; t < 4; t++) {
                af[t].u = *(const uint4*)&Abuf[aoff[t] ^ (k0 << 5)];
                bf[t].u = *(const uint4*)&Bbuf[boff[t] ^ (k0 << 5)];
            }
            #pragma unroll
            for (int i = 0; i < 4; i++)
                #pragma unroll
                for (int j = 0; j < 4; j++)
                    acc[i][j] = __builtin_amdgcn_mfma_f32_16x16x32_bf16(
                        af[i].s, bf[j].s, acc[i][j], 0, 0, 0);
        }
        Ag += 64; Bg += 64;
    }
}

// XCD-bijective chunked remap: consecutive f within one XCD.
__device__ __forceinline__ int xcd_remap(int bid, int nwg) {
    int q8 = nwg >> 3, r8 = nwg & 7;
    int xcd = bid & 7, loc = bid >> 3;
    return (xcd < r8 ? xcd * (q8 + 1) : r8 * (q8 + 1) + (xcd - r8) * q8) + loc;
}

// GEMM1: xh[MR,768] * wh[2304,768]^T -> qbf (scaled), kbf, vbf.
// 1782 blocks; per-XCD chunk = ~12 m-rows x 18 n (A-chunk 2.5MB + B 3.5MB in L2).
__global__ __launch_bounds__(256) void gemm_qkv_mfma(
    const ushort_t* __restrict__ A2, const ushort_t* __restrict__ B2,
    ushort_t* __restrict__ qbf, ushort_t* __restrict__ kbf,
    ushort_t* __restrict__ vbf)
{
    __shared__ ushort_t Abuf[128 * 64];
    __shared__ ushort_t Bbuf[128 * 64];
    f32x4 acc[4][4];
    f32x4 z = {0.f, 0.f, 0.f, 0.f};
    #pragma unroll
    for (int i = 0; i < 4; i++)
        #pragma unroll
        for (int j = 0; j < 4; j++) acc[i][j] = z;

    int f = xcd_remap(blockIdx.x, 1782);
    int mt_ = f / 18, nt_ = f - mt_ * 18;
    const int m0 = mt_ * 128, n0 = nt_ * 128;
    gemm_mainloop(A2, NC, B2, NC, m0, n0, 12, Abuf, Bbuf, acc);

    __syncthreads();                         // Abuf free for reuse as scratch

    const int tid = threadIdx.x;
    const int w = tid >> 6, lane = tid & 63;
    const int wm = w & 1, wn = w >> 1;
    const int quad = lane >> 4, l15 = lane & 15;

    // wave-constant output decomposition (64-col span never crosses 768)
    int c0b = n0 + wn * 64;
    int tq = c0b / NC;
    int wi = c0b - tq * NC;
    int hh = wi >> 6;
    ushort_t* dst = (tq == 0) ? qbf : (tq == 1) ? kbf : vbf;
    float scale = (tq == 0) ? 0.125f : 1.0f;

    // per-wave LDS transpose: 16 rows x 64 d, stride 72 ushorts (144B)
    ushort_t* Sw = Abuf + w * 1152;
    const int orow = lane >> 2;
    const int dch = (lane & 3) << 3;         // 0,8,16,24
    #pragma unroll
    for (int mt = 0; mt < 4; mt++) {
        #pragma unroll
        for (int nt = 0; nt < 4; nt++)
            #pragma unroll
            for (int r = 0; r < 4; r++)
                Sw[(quad * 4 + r) * 72 + nt * 16 + l15] =
                    (ushort_t)bf16_rne(acc[mt][nt][r] * scale);
        int m = m0 + wm * 64 + mt * 16 + orow;
        if (m < MM) {
            int b_ = m / NN, n_ = m - b_ * NN;
            size_t rb = ((size_t)(b_ * NH + hh) * NN + n_) * HD;
            uint4 v0 = *(const uint4*)&Sw[orow * 72 + dch];
            uint4 v1 = *(const uint4*)&Sw[orow * 72 + dch + 32];
            *(uint4*)&dst[rb + dch] = v0;
            *(uint4*)&dst[rb + dch + 32] = v1;
        }
    }
}

// GEMM2: ab[MR,768] * wp[768,768]^T + bias -> out fp32. 594 blocks.
__global__ __launch_bounds__(256) void gemm_proj_mfma(
    const ushort_t* __restrict__ A2, const ushort_t* __restrict__ B2,
    const float* __restrict__ bias, float* __restrict__ out)
{
    __shared__ ushort_t Abuf[128 * 64];
    __shared__ ushort_t Bbuf[128 * 64];
    f32x4 acc[4][4];
    f32x4 z = {0.f, 0.f, 0.f, 0.f};
    #pragma unroll
    for (int i = 0; i < 4; i++)
        #pragma unroll
        for (int j = 0; j < 4; j++) acc[i][j] = z;

    int f = xcd_remap(blockIdx.x, 594);
    int mt_ = f / 6, nt_ = f - mt_ * 6;
    const int m0 = mt_ * 128, n0 = nt_ * 128;
    gemm_mainloop(A2, NC, B2, NC, m0, n0, 12, Abuf, Bbuf, acc);

    const int tid = threadIdx.x;
    const int w = tid >> 6, lane = tid & 63;
    const int wm = w & 1, wn = w >> 1;
    const int quad = lane >> 4, l15 = lane & 15;
    #pragma unroll
    for (int nt = 0; nt < 4; nt++) {
        int col = n0 + wn * 64 + nt * 16 + l15;
        float bi = bias[col];
        #pragma unroll
        for (int mt = 0; mt < 4; mt++) {
            #pragma unroll
            for (int r = 0; r < 4; r++) {
                int m = m0 + wm * 64 + mt * 16 + quad * 4 + r;
                if (m < MM)
                    out[(size_t)m * NC + col] = acc[mt][nt][r] + bi;
            }
        }
    }
}

// ---------------------------------------------------------------------------
// MFMA attention. grid 768 x 256 threads (4 waves). One block per (b,h).
// LDS 54272 B -> 3 blocks/CU. K-frags batch-loaded (13 regs) per half so
// global latency is exposed once per half, not per kt.
// ---------------------------------------------------------------------------
__global__ __launch_bounds__(256, 3) void attn_mfma(
    const ushort_t* __restrict__ qbf, const ushort_t* __restrict__ kbf,
    const ushort_t* __restrict__ vbf, const float* __restrict__ biasP,
    ushort_t* __restrict__ ab)
{
    __shared__ ushort_t Vt[64 * VTS];        // Vt[d][key], 27648 B
    __shared__ ushort_t Pl[4][16 * PS];      // per-wave P / V-stage / O-transpose

    const int bh = blockIdx.x;
    const int b = bh / NH, h = bh % NH;
    const int tid = threadIdx.x;
    const int w = tid >> 6, lane = tid & 63;
    const int quad = lane >> 4, l15 = lane & 15;
    const size_t base = (size_t)bh * (NN * HD);
    const ushort_t* kg = kbf + base;
    const ushort_t* vg = vbf + base;
    const ushort_t* qg = qbf + base;

    // stage V row-major coalesced, then LDS->LDS transpose into Vt
    ushort_t* Vstage = &Pl[0][0];            // 208*64 ushorts = Pl exactly
    for (int idx = tid; idx < NP * 8; idx += 256) {
        int row = idx >> 3, ch = idx & 7;
        uint4 val = {0u, 0u, 0u, 0u};
        if (row < NN) val = *(const uint4*)(vg + (size_t)row * HD + ch * 8);
        *(uint4*)&Vstage[row * HD + ch * 8] = val;
    }
    __syncthreads();
    for (int task = tid; task < 64 * 26; task += 256) {
        int d = task & 63, kc = task >> 6;
        ushort_t tmp[8];
        #pragma unroll
        for (int j = 0; j < 8; j++)
            tmp[j] = Vstage[(kc * 8 + j) * HD + d];
        uint4 u;
        u.x = (unsigned)tmp[0] | ((unsigned)tmp[1] << 16);
        u.y = (unsigned)tmp[2] | ((unsigned)tmp[3] << 16);
        u.z = (unsigned)tmp[4] | ((unsigned)tmp[5] << 16);
        u.w = (unsigned)tmp[6] | ((unsigned)tmp[7] << 16);
        *(uint4*)&Vt[d * VTS + kc * 8] = u;
    }
    __syncthreads();                         // Vt ready; Pl free

    #pragma unroll
    for (int rep = 0; rep < 4; rep++) {
        int qt = w + rep * 4;
        if (qt > 12) break;
        const int q0 = qt * 16;

        int qrow = q0 + l15; if (qrow > NN - 1) qrow = NN - 1;
        U128 qf0, qf1;
        qf0.u = *(const uint4*)(qg + (size_t)qrow * HD + quad * 8);
        qf1.u = *(const uint4*)(qg + (size_t)qrow * HD + 32 + quad * 8);

        // S init from biasP: 13 independent float4 loads
        f32x4 S[13];
        const float* bp = biasP + ((size_t)(h * 13 + qt) * 13) * 256 + (quad << 6) + (l15 << 2);
        #pragma unroll
        for (int kt = 0; kt < 13; kt++) {
            float4 bv = *(const float4*)(bp + kt * 256);
            S[kt][0] = bv.x; S[kt][1] = bv.y; S[kt][2] = bv.z; S[kt][3] = bv.w;
        }

        // QK^T: batch all 13 K-frag loads per half, then 13 MFMAs.
        {
            U128 kf[13];
            #pragma unroll
            for (int kt = 0; kt < 13; kt++) {
                int krow = kt * 16 + l15; if (krow > NN - 1) krow = NN - 1;
                kf[kt].u = *(const uint4*)(kg + (size_t)krow * HD + quad * 8);
            }
            #pragma unroll
            for (int kt = 0; kt < 13; kt++)
                S[kt] = __builtin_amdgcn_mfma_f32_16x16x32_bf16(qf0.s, kf[kt].s, S[kt], 0, 0, 0);
            #pragma unroll
            for (int kt = 0; kt < 13; kt++) {
                int krow = kt * 16 + l15; if (krow > NN - 1) krow = NN - 1;
                kf[kt].u = *(const uint4*)(kg + (size_t)krow * HD + 32 + quad * 8);
            }
            #pragma unroll
            for (int kt = 0; kt < 13; kt++)
                S[kt] = __builtin_amdgcn_mfma_f32_16x16x32_bf16(qf1.s, kf[kt].s, S[kt], 0, 0, 0);
        }

        // softmax (rows quad*4+r over 16 l15 lanes x 13 tiles)
        ushort_t* P = Pl[w];
        #pragma unroll
        for (int r = 0; r < 4; r++) {
            float mx = S[0][r];
            #pragma unroll
            for (int kt = 1; kt < 13; kt++) mx = fmaxf(mx, S[kt][r]);
            mx = fmaxf(mx, __shfl_xor(mx, 1));
            mx = fmaxf(mx, __shfl_xor(mx, 2));
            mx = fmaxf(mx, __shfl_xor(mx, 4));
            mx = fmaxf(mx, __shfl_xor(mx, 8));
            float sum = 0.f;
            #pragma unroll
            for (int kt = 0; kt < 13; kt++) {
                float e = __expf(S[kt][r] - mx);
                S[kt][r] = e;
                sum += e;
            }
            sum += __shfl_xor(sum, 1);
            sum += __shfl_xor(sum, 2);
            sum += __shfl_xor(sum, 4);
            sum += __shfl_xor(sum, 8);
            float inv = 1.0f / sum;
            int prow = quad * 4 + r;
            #pragma unroll
            for (int kt = 0; kt < 13; kt++)
                P[prow * PS + kt * 16 + l15] = (ushort_t)bf16_rne(S[kt][r] * inv);
        }

        // PV: 7 chunks of 32 keys; chunk 6 keys 208..223 masked to 0.
        f32x4 O[4];
        f32x4 z4 = {0.f, 0.f, 0.f, 0.f};
        #pragma unroll
        for (int dt = 0; dt < 4; dt++) O[dt] = z4;
        #pragma unroll
        for (int ks = 0; ks < 7; ks++) {
            int pc = ks * 32 + quad * 8;
            bool vld = (pc < NP);
            int pcc = vld ? pc : 0;
            U128 pf;
            pf.u = *(const uint4*)&P[l15 * PS + pcc];
            if (!vld) { pf.u.x = 0u; pf.u.y = 0u; pf.u.z = 0u; pf.u.w = 0u; }
            #pragma unroll
            for (int dt = 0; dt < 4; dt++) {
                U128 vf;
                vf.u = *(const uint4*)&Vt[(dt * 16 + l15) * VTS + pcc];
                O[dt] = __builtin_amdgcn_mfma_f32_16x16x32_bf16(pf.s, vf.s, O[dt], 0, 0, 0);
            }
        }

        // epilogue: transpose O through wave-private LDS, emit b128 bf16 hi
        float* Osh = (float*)&Pl[w][0];      // stride 68 floats
        #pragma unroll
        for (int dt = 0; dt < 4; dt++)
            #pragma unroll
            for (int r = 0; r < 4; r++)
                Osh[(quad * 4 + r) * 68 + dt * 16 + l15] = O[dt][r];
        int orow = lane >> 2;
        int d0 = (lane & 3) << 4;
        int q = q0 + orow;
        if (q < NN) {
            unsigned hiw[8];
            #pragma unroll
            for (int k4 = 0; k4 < 4; k4++) {
                float4 f = *(const float4*)&Osh[orow * 68 + d0 + k4 * 4];
                unsigned h0 = bf16_rne(f.x), h1 = bf16_rne(f.y);
                unsigned h2 = bf16_rne(f.z), h3 = bf16_rne(f.w);
                hiw[k4 * 2]     = h0 | (h1 << 16);
                hiw[k4 * 2 + 1] = h2 | (h3 << 16);
            }
            size_t baseo = ((size_t)b * NN + q) * NC + h * HD + d0;
            uint4 hA = {hiw[0], hiw[1], hiw[2], hiw[3]};
            uint4 hB = {hiw[4], hiw[5], hiw[6], hiw[7]};
            *(uint4*)&ab[baseo] = hA;
            *(uint4*)&ab[baseo + 8] = hB;
        }
    }
}

// ---------------------------------------------------------------------------
extern "C" void kernel_launch(void* const* d_in, const int* in_sizes, int n_in,
                              void* d_out, int out_size, void* d_ws, size_t ws_size,
                              hipStream_t stream)
{
    const float* x        = (const float*)d_in[0];
    const float* table    = (const float*)d_in[1];
    const float* w_qkv    = (const float*)d_in[2];
    const float* w_proj   = (const float*)d_in[3];
    const float* b_proj   = (const float*)d_in[4];
    const int*   rel_idx  = (const int*)d_in[5];
    float* out = (float*)d_out;

    ushort_t* xh  = (ushort_t*)d_ws;                        // MR*768
    ushort_t* wh  = xh + (size_t)MR * NC;                   // 2304*768
    ushort_t* wp  = wh + (size_t)2304 * NC;                 // 768*768
    ushort_t* ab  = wp + (size_t)768 * NC;                  // MR*768
    ushort_t* qbf = ab + (size_t)MR * NC;                   // SZQ each
    ushort_t* kbf = qbf + SZQ;
    ushort_t* vbf = kbf + SZQ;
    float* biasP  = (float*)(vbf + SZQ);                    // BIASN f32

    const int ptot = CVTQ + BIASN;
    prepare<<<(ptot + 255) / 256, 256, 0, stream>>>(
        x, w_qkv, w_proj, table, rel_idx, xh, wh, wp, biasP);

    gemm_qkv_mfma<<<1782, 256, 0, stream>>>(xh, wh, qbf, kbf, vbf);
    attn_mfma<<<768, 256, 0, stream>>>(qbf, kbf, vbf, biasP, ab);
    gemm_proj_mfma<<<594, 256, 0, stream>>>(ab, wp, b_proj, out);
}

// Round 8
// 249.949 us; speedup vs baseline: 1.1829x; 1.1197x over previous
//
#include <hip/hip_runtime.h>

// Shapes: B=64, N=197, C=768, H=12, hd=64
// qkv/proj GEMM: plain bf16 (K=768), 128^2 m97-structure, XCD-chunked
//   bijective swizzle, qkv epilogue via per-wave LDS transpose.
// Attention: MFMA flash-lite. K staged into LDS per block (reg-staged
//   ds_write_b128, GEMM-swizzle layout; NOT global_load_lds -- r6/r7 infra
//   failures, de-risked); QK^T fragments become ds_read_b128. Vt/P strides
//   208 (216 measured worse, r5). LDS 79872 B -> 2 blocks/CU.
// prepare = fused convert + bias gather.

#define NB   64
#define NN   197
#define NC   768
#define NH   12
#define HD   64
#define MM   (NB*NN)      // 12608
#define MR   12672        // 99*128
#define NP   208          // 13*16
#define PS   208          // P / Vt row stride (ushorts)
#define SZQ  ((size_t)NB * NH * NN * HD)
#define CVTQ ((MM + 2304 + 768) * 192)
#define BIASN (NH * 13 * 13 * 256)

typedef unsigned short ushort_t;
typedef __attribute__((ext_vector_type(8))) short short8;
typedef __attribute__((ext_vector_type(4))) float f32x4;
union U128 { uint4 u; short8 s; };

__device__ __forceinline__ unsigned bf16_rne(float f) {
    unsigned u = __float_as_uint(f);
    return (u + 0x7fffu + ((u >> 16) & 1u)) >> 16;
}

__device__ __forceinline__ void gld16(unsigned short* lds, const unsigned short* g) {
    __builtin_amdgcn_global_load_lds(
        (const __attribute__((address_space(1))) void*)g,
        (__attribute__((address_space(3))) void*)lds, 16, 0, 0);
}

// ---------------------------------------------------------------------------
// prepare: x->xh, w_qkv->wh, w_proj->wp (bf16) AND biasP fragment gather.
// ---------------------------------------------------------------------------
__global__ __launch_bounds__(256) void prepare(
    const float* __restrict__ x, const float* __restrict__ w_qkv,
    const float* __restrict__ w_proj, const float* __restrict__ table,
    const int* __restrict__ rel_index,
    ushort_t* __restrict__ xh, ushort_t* __restrict__ wh,
    ushort_t* __restrict__ wp, float* __restrict__ biasP)
{
    int idx = blockIdx.x * 256 + threadIdx.x;
    if (idx < CVTQ) {
        int r = idx / 192;
        int c = (idx - r * 192) * 4;
        const float* src;
        ushort_t* dsth;
        if (r < MM) {
            src = x + (size_t)r * NC; dsth = xh + (size_t)r * NC + c;
        } else if (r < MM + 2304) {
            int rr = r - MM;
            src = w_qkv + (size_t)rr * NC; dsth = wh + (size_t)rr * NC + c;
        } else {
            int rr = r - MM - 2304;
            src = w_proj + (size_t)rr * NC; dsth = wp + (size_t)rr * NC + c;
        }
        float4 f = *(const float4*)(src + c);
        ushort4 hv = { (ushort_t)bf16_rne(f.x), (ushort_t)bf16_rne(f.y),
                       (ushort_t)bf16_rne(f.z), (ushort_t)bf16_rne(f.w) };
        *(ushort4*)dsth = hv;
    } else {
        int i = idx - CVTQ;
        if (i < BIASN) {
            int r = i & 3, l15 = (i >> 2) & 15, quad = (i >> 6) & 3;
            int t = i >> 8;
            int kt = t % 13; int t2 = t / 13;
            int qt = t2 % 13; int h = t2 / 13;
            int n = qt * 16 + quad * 4 + r;
            int m = kt * 16 + l15;
            float v = -1e30f;
            if (n < NN && m < NN) v = table[rel_index[n * NN + m] * NH + h];
            biasP[i] = v;
        }
    }
}

// ---------------------------------------------------------------------------
// bf16 MFMA mainloop; strides + kiters parameterized. 128^2, 4 waves.
// ---------------------------------------------------------------------------
__device__ __forceinline__ void gemm_mainloop(
    const ushort_t* __restrict__ A2, int sA,
    const ushort_t* __restrict__ B2, int sB,
    int m0, int n0, int kiters, ushort_t* Abuf, ushort_t* Bbuf, f32x4 acc[4][4])
{
    const int tid = threadIdx.x;
    const int w = tid >> 6, lane = tid & 63;
    const int wm = w & 1, wn = w >> 1;
    const int lr = lane >> 3, lc = lane & 7;
    const int gch = lc ^ lr;

    const ushort_t* Ag = A2 + (size_t)(m0 + w * 32 + lr) * sA + gch * 8;
    const ushort_t* Bg = B2 + (size_t)(n0 + w * 32 + lr) * sB + gch * 8;
    ushort_t* Al = Abuf + (w * 32) * 64;
    ushort_t* Bl = Bbuf + (w * 32) * 64;

    int aoff[4], boff[4];
    const int quad = lane >> 4, l15 = lane & 15;
    #pragma unroll
    for (int t = 0; t < 4; t++) {
        int ra = wm * 64 + t * 16 + l15;
        aoff[t] = ra * 64 + ((quad ^ (ra & 7)) << 3);
        int rb = wn * 64 + t * 16 + l15;
        boff[t] = rb * 64 + ((quad ^ (rb & 7)) << 3);
    }

    for (int ks = 0; ks < kiters; ks++) {
        __syncthreads();
        #pragma unroll
        for (int it = 0; it < 4; it++) {
            gld16(Al + it * 8 * 64, Ag + (size_t)it * 8 * sA);
            gld16(Bl + it * 8 * 64, Bg + (size_t)it * 8 * sB);
        }
        __syncthreads();
        #pragma unroll
        for (int k0 = 0; k0 < 2; k0++) {
            U128 af[4], bf[4];
            #pragma unroll
            for (int t = 0; t < 4; t++) {
                af[t].u = *(const uint4*)&Abuf[aoff[t] ^ (k0 << 5)];
                bf[t].u = *(const uint4*)&Bbuf[boff[t] ^ (k0 << 5)];
            }
            #pragma unroll
            for (int i = 0; i < 4; i++)
                #pragma unroll
                for (int j = 0; j < 4; j++)
                    acc[i][j] = __builtin_amdgcn_mfma_f32_16x16x32_bf16(
                        af[i].s, bf[j].s, acc[i][j], 0, 0, 0);
        }
        Ag += 64; Bg += 64;
    }
}

// XCD-bijective chunked remap: consecutive f within one XCD.
__device__ __forceinline__ int xcd_remap(int bid, int nwg) {
    int q8 = nwg >> 3, r8 = nwg & 7;
    int xcd = bid & 7, loc = bid >> 3;
    return (xcd < r8 ? xcd * (q8 + 1) : r8 * (q8 + 1) + (xcd - r8) * q8) + loc;
}

// GEMM1: xh[MR,768] * wh[2304,768]^T -> qbf (scaled), kbf, vbf. 1782 blocks.
__global__ __launch_bounds__(256) void gemm_qkv_mfma(
    const ushort_t* __restrict__ A2, const ushort_t* __restrict__ B2,
    ushort_t* __restrict__ qbf, ushort_t* __restrict__ kbf,
    ushort_t* __restrict__ vbf)
{
    __shared__ ushort_t Abuf[128 * 64];
    __shared__ ushort_t Bbuf[128 * 64];
    f32x4 acc[4][4];
    f32x4 z = {0.f, 0.f, 0.f, 0.f};
    #pragma unroll
    for (int i = 0; i < 4; i++)
        #pragma unroll
        for (int j = 0; j < 4; j++) acc[i][j] = z;

    int f = xcd_remap(blockIdx.x, 1782);
    int mt_ = f / 18, nt_ = f - mt_ * 18;
    const int m0 = mt_ * 128, n0 = nt_ * 128;
    gemm_mainloop(A2, NC, B2, NC, m0, n0, 12, Abuf, Bbuf, acc);

    __syncthreads();                         // Abuf free for reuse as scratch

    const int tid = threadIdx.x;
    const int w = tid >> 6, lane = tid & 63;
    const int wm = w & 1, wn = w >> 1;
    const int quad = lane >> 4, l15 = lane & 15;

    int c0b = n0 + wn * 64;
    int tq = c0b / NC;
    int wi = c0b - tq * NC;
    int hh = wi >> 6;
    ushort_t* dst = (tq == 0) ? qbf : (tq == 1) ? kbf : vbf;
    float scale = (tq == 0) ? 0.125f : 1.0f;

    ushort_t* Sw = Abuf + w * 1152;
    const int orow = lane >> 2;
    const int dch = (lane & 3) << 3;
    #pragma unroll
    for (int mt = 0; mt < 4; mt++) {
        #pragma unroll
        for (int nt = 0; nt < 4; nt++)
            #pragma unroll
            for (int r = 0; r < 4; r++)
                Sw[(quad * 4 + r) * 72 + nt * 16 + l15] =
                    (ushort_t)bf16_rne(acc[mt][nt][r] * scale);
        int m = m0 + wm * 64 + mt * 16 + orow;
        if (m < MM) {
            int b_ = m / NN, n_ = m - b_ * NN;
            size_t rb = ((size_t)(b_ * NH + hh) * NN + n_) * HD;
            uint4 v0 = *(const uint4*)&Sw[orow * 72 + dch];
            uint4 v1 = *(const uint4*)&Sw[orow * 72 + dch + 32];
            *(uint4*)&dst[rb + dch] = v0;
            *(uint4*)&dst[rb + dch + 32] = v1;
        }
    }
}

// GEMM2: ab[MR,768] * wp[768,768]^T + bias -> out fp32. 594 blocks.
__global__ __launch_bounds__(256) void gemm_proj_mfma(
    const ushort_t* __restrict__ A2, const ushort_t* __restrict__ B2,
    const float* __restrict__ bias, float* __restrict__ out)
{
    __shared__ ushort_t Abuf[128 * 64];
    __shared__ ushort_t Bbuf[128 * 64];
    f32x4 acc[4][4];
    f32x4 z = {0.f, 0.f, 0.f, 0.f};
    #pragma unroll
    for (int i = 0; i < 4; i++)
        #pragma unroll
        for (int j = 0; j < 4; j++) acc[i][j] = z;

    int f = xcd_remap(blockIdx.x, 594);
    int mt_ = f / 6, nt_ = f - mt_ * 6;
    const int m0 = mt_ * 128, n0 = nt_ * 128;
    gemm_mainloop(A2, NC, B2, NC, m0, n0, 12, Abuf, Bbuf, acc);

    const int tid = threadIdx.x;
    const int w = tid >> 6, lane = tid & 63;
    const int wm = w & 1, wn = w >> 1;
    const int quad = lane >> 4, l15 = lane & 15;
    #pragma unroll
    for (int nt = 0; nt < 4; nt++) {
        int col = n0 + wn * 64 + nt * 16 + l15;
        float bi = bias[col];
        #pragma unroll
        for (int mt = 0; mt < 4; mt++) {
            #pragma unroll
            for (int r = 0; r < 4; r++) {
                int m = m0 + wm * 64 + mt * 16 + quad * 4 + r;
                if (m < MM)
                    out[(size_t)m * NC + col] = acc[mt][nt][r] + bi;
            }
        }
    }
}

// ---------------------------------------------------------------------------
// MFMA attention. grid 768 x 256 threads (4 waves). One block per (b,h).
// K reg-staged into LDS (swizzled ds_write_b128); QK^T reads ds_read_b128.
// LDS 79872 B -> 2 blocks/CU.
// ---------------------------------------------------------------------------
__global__ __launch_bounds__(256) void attn_mfma(
    const ushort_t* __restrict__ qbf, const ushort_t* __restrict__ kbf,
    const ushort_t* __restrict__ vbf, const float* __restrict__ biasP,
    ushort_t* __restrict__ ab)
{
    __shared__ ushort_t Kl[NP * 64];         // 26624 B, GEMM-swizzle layout
    __shared__ ushort_t Vt[64 * PS];         // Vt[d][key], 26624 B
    __shared__ ushort_t Pl[4][16 * PS];      // per-wave P / V-stage / O-transpose

    const int bh = blockIdx.x;
    const int b = bh / NH, h = bh % NH;
    const int tid = threadIdx.x;
    const int w = tid >> 6, lane = tid & 63;
    const int quad = lane >> 4, l15 = lane & 15;
    const size_t base = (size_t)bh * (NN * HD);
    const ushort_t* kg = kbf + base;
    const ushort_t* vg = vbf + base;
    const ushort_t* qg = qbf + base;

    // ---- K stage: global -> reg -> swizzled LDS ----
    // Kl[row][slot s] = K[row][chunk s ^ (row&7)]; rows >= NN duplicate row
    // NN-1 (finite) -- neutralized by -1e30 bias in softmax.
    for (int idx = tid; idx < NP * 8; idx += 256) {
        int row = idx >> 3, ch = idx & 7;
        int srow = (row < NN) ? row : (NN - 1);
        uint4 val = *(const uint4*)(kg + (size_t)srow * HD + ch * 8);
        *(uint4*)&Kl[row * 64 + ((ch ^ (row & 7)) << 3)] = val;
    }

    // ---- stage V row-major coalesced, then LDS->LDS transpose into Vt ----
    ushort_t* Vstage = &Pl[0][0];            // 208*64 ushorts = Pl exactly
    for (int idx = tid; idx < NP * 8; idx += 256) {
        int row = idx >> 3, ch = idx & 7;
        uint4 val = {0u, 0u, 0u, 0u};
        if (row < NN) val = *(const uint4*)(vg + (size_t)row * HD + ch * 8);
        *(uint4*)&Vstage[row * HD + ch * 8] = val;
    }
    __syncthreads();                         // Kl + Vstage complete
    for (int task = tid; task < 64 * 26; task += 256) {
        int d = task & 63, kc = task >> 6;
        ushort_t tmp[8];
        #pragma unroll
        for (int j = 0; j < 8; j++)
            tmp[j] = Vstage[(kc * 8 + j) * HD + d];
        uint4 u;
        u.x = (unsigned)tmp[0] | ((unsigned)tmp[1] << 16);
        u.y = (unsigned)tmp[2] | ((unsigned)tmp[3] << 16);
        u.z = (unsigned)tmp[4] | ((unsigned)tmp[5] << 16);
        u.w = (unsigned)tmp[6] | ((unsigned)tmp[7] << 16);
        *(uint4*)&Vt[d * PS + kc * 8] = u;
    }
    __syncthreads();                         // Vt ready; Pl free

    const int ksl = (quad ^ (l15 & 7)) << 3; // K fragment slot (matches stage)

    #pragma unroll
    for (int rep = 0; rep < 4; rep++) {
        int qt = w + rep * 4;
        if (qt > 12) break;
        const int q0 = qt * 16;

        int qrow = q0 + l15; if (qrow > NN - 1) qrow = NN - 1;
        U128 qf0, qf1;
        qf0.u = *(const uint4*)(qg + (size_t)qrow * HD + quad * 8);
        qf1.u = *(const uint4*)(qg + (size_t)qrow * HD + 32 + quad * 8);

        // S init from biasP: 13 independent float4 loads
        f32x4 S[13];
        const float* bp = biasP + ((size_t)(h * 13 + qt) * 13) * 256 + (quad << 6) + (l15 << 2);
        #pragma unroll
        for (int kt = 0; kt < 13; kt++) {
            float4 bv = *(const float4*)(bp + kt * 256);
            S[kt][0] = bv.x; S[kt][1] = bv.y; S[kt][2] = bv.z; S[kt][3] = bv.w;
        }

        // QK^T: K fragments from LDS (conflict-free GEMM pattern)
        #pragma unroll
        for (int kt = 0; kt < 13; kt++) {
            int ro = (kt * 16 + l15) * 64 + ksl;
            U128 k0, k1;
            k0.u = *(const uint4*)&Kl[ro];
            k1.u = *(const uint4*)&Kl[ro ^ 32];
            S[kt] = __builtin_amdgcn_mfma_f32_16x16x32_bf16(qf0.s, k0.s, S[kt], 0, 0, 0);
            S[kt] = __builtin_amdgcn_mfma_f32_16x16x32_bf16(qf1.s, k1.s, S[kt], 0, 0, 0);
        }

        // softmax (rows quad*4+r over 16 l15 lanes x 13 tiles)
        ushort_t* P = Pl[w];
        #pragma unroll
        for (int r = 0; r < 4; r++) {
            float mx = S[0][r];
            #pragma unroll
            for (int kt = 1; kt < 13; kt++) mx = fmaxf(mx, S[kt][r]);
            mx = fmaxf(mx, __shfl_xor(mx, 1));
            mx = fmaxf(mx, __shfl_xor(mx, 2));
            mx = fmaxf(mx, __shfl_xor(mx, 4));
            mx = fmaxf(mx, __shfl_xor(mx, 8));
            float sum = 0.f;
            #pragma unroll
            for (int kt = 0; kt < 13; kt++) {
                float e = __expf(S[kt][r] - mx);
                S[kt][r] = e;
                sum += e;
            }
            sum += __shfl_xor(sum, 1);
            sum += __shfl_xor(sum, 2);
            sum += __shfl_xor(sum, 4);
            sum += __shfl_xor(sum, 8);
            float inv = 1.0f / sum;
            int prow = quad * 4 + r;
            #pragma unroll
            for (int kt = 0; kt < 13; kt++)
                P[prow * PS + kt * 16 + l15] = (ushort_t)bf16_rne(S[kt][r] * inv);
        }

        // PV: 7 chunks of 32 keys; chunk 6 keys 208..223 masked to 0.
        f32x4 O[4];
        f32x4 z4 = {0.f, 0.f, 0.f, 0.f};
        #pragma unroll
        for (int dt = 0; dt < 4; dt++) O[dt] = z4;
        #pragma unroll
        for (int ks = 0; ks < 7; ks++) {
            int pc = ks * 32 + quad * 8;
            bool vld = (pc < NP);
            int pcc = vld ? pc : 0;
            U128 pf;
            pf.u = *(const uint4*)&P[l15 * PS + pcc];
            if (!vld) { pf.u.x = 0u; pf.u.y = 0u; pf.u.z = 0u; pf.u.w = 0u; }
            #pragma unroll
            for (int dt = 0; dt < 4; dt++) {
                U128 vf;
                vf.u = *(const uint4*)&Vt[(dt * 16 + l15) * PS + pcc];
                O[dt] = __builtin_amdgcn_mfma_f32_16x16x32_bf16(pf.s, vf.s, O[dt], 0, 0, 0);
            }
        }

        // epilogue: transpose O through wave-private LDS, emit b128 bf16 hi
        float* Osh = (float*)&Pl[w][0];      // stride 68 floats
        #pragma unroll
        for (int dt = 0; dt < 4; dt++)
            #pragma unroll
            for (int r = 0; r < 4; r++)
                Osh[(quad * 4 + r) * 68 + dt * 16 + l15] = O[dt][r];
        int orow = lane >> 2;
        int d0 = (lane & 3) << 4;
        int q = q0 + orow;
        if (q < NN) {
            unsigned hiw[8];
            #pragma unroll
            for (int k4 = 0; k4 < 4; k4++) {
                float4 f = *(const float4*)&Osh[orow * 68 + d0 + k4 * 4];
                unsigned h0 = bf16_rne(f.x), h1 = bf16_rne(f.y);
                unsigned h2 = bf16_rne(f.z), h3 = bf16_rne(f.w);
                hiw[k4 * 2]     = h0 | (h1 << 16);
                hiw[k4 * 2 + 1] = h2 | (h3 << 16);
            }
            size_t baseo = ((size_t)b * NN + q) * NC + h * HD + d0;
            uint4 hA = {hiw[0], hiw[1], hiw[2], hiw[3]};
            uint4 hB = {hiw[4], hiw[5], hiw[6], hiw[7]};
            *(uint4*)&ab[baseo] = hA;
            *(uint4*)&ab[baseo + 8] = hB;
        }
    }
}

// ---------------------------------------------------------------------------
extern "C" void kernel_launch(void* const* d_in, const int* in_sizes, int n_in,
                              void* d_out, int out_size, void* d_ws, size_t ws_size,
                              hipStream_t stream)
{
    const float* x        = (const float*)d_in[0];
    const float* table    = (const float*)d_in[1];
    const float* w_qkv    = (const float*)d_in[2];
    const float* w_proj   = (const float*)d_in[3];
    const float* b_proj   = (const float*)d_in[4];
    const int*   rel_idx  = (const int*)d_in[5];
    float* out = (float*)d_out;

    ushort_t* xh  = (ushort_t*)d_ws;                        // MR*768
    ushort_t* wh  = xh + (size_t)MR * NC;                   // 2304*768
    ushort_t* wp  = wh + (size_t)2304 * NC;                 // 768*768
    ushort_t* ab  = wp + (size_t)768 * NC;                  // MR*768
    ushort_t* qbf = ab + (size_t)MR * NC;                   // SZQ each
    ushort_t* kbf = qbf + SZQ;
    ushort_t* vbf = kbf + SZQ;
    float* biasP  = (float*)(vbf + SZQ);                    // BIASN f32

    const int ptot = CVTQ + BIASN;
    prepare<<<(ptot + 255) / 256, 256, 0, stream>>>(
        x, w_qkv, w_proj, table, rel_idx, xh, wh, wp, biasP);

    gemm_qkv_mfma<<<1782, 256, 0, stream>>>(xh, wh, qbf, kbf, vbf);
    attn_mfma<<<768, 256, 0, stream>>>(qbf, kbf, vbf, biasP, ab);
    gemm_proj_mfma<<<594, 256, 0, stream>>>(ab, wp, b_proj, out);
}

// Round 9
// 228.905 us; speedup vs baseline: 1.2916x; 1.0919x over previous
//
#include <hip/hip_runtime.h>

// Shapes: B=64, N=197, C=768, H=12, hd=64
// qkv/proj GEMM: plain bf16 (K=768), 128x256 tile (acc[4][8]): 64 MFMA per
//   thread per K-step vs 32 -- halves the barrier-drain share that capped the
//   128^2 structure at MfmaUtil 25%. LDS 48KB, VGPR ~200 -> 2 blocks/CU
//   (same residency as measured r8). XCD-chunked bijective swizzle.
//   qkv epilogue via per-wave LDS transpose -> coalesced uint4 stores.
// Attention: MFMA flash-lite, K reg-staged into swizzled LDS (r8, works).
// prepare = fused convert + bias gather.

#define NB   64
#define NN   197
#define NC   768
#define NH   12
#define HD   64
#define MM   (NB*NN)      // 12608
#define MR   12672        // 99*128
#define NP   208          // 13*16
#define PS   208          // P / Vt row stride (ushorts)
#define SZQ  ((size_t)NB * NH * NN * HD)
#define CVTQ ((MM + 2304 + 768) * 192)
#define BIASN (NH * 13 * 13 * 256)

typedef unsigned short ushort_t;
typedef __attribute__((ext_vector_type(8))) short short8;
typedef __attribute__((ext_vector_type(4))) float f32x4;
union U128 { uint4 u; short8 s; };

__device__ __forceinline__ unsigned bf16_rne(float f) {
    unsigned u = __float_as_uint(f);
    return (u + 0x7fffu + ((u >> 16) & 1u)) >> 16;
}

__device__ __forceinline__ void gld16(unsigned short* lds, const unsigned short* g) {
    __builtin_amdgcn_global_load_lds(
        (const __attribute__((address_space(1))) void*)g,
        (__attribute__((address_space(3))) void*)lds, 16, 0, 0);
}

// ---------------------------------------------------------------------------
// prepare: x->xh, w_qkv->wh, w_proj->wp (bf16) AND biasP fragment gather.
// ---------------------------------------------------------------------------
__global__ __launch_bounds__(256) void prepare(
    const float* __restrict__ x, const float* __restrict__ w_qkv,
    const float* __restrict__ w_proj, const float* __restrict__ table,
    const int* __restrict__ rel_index,
    ushort_t* __restrict__ xh, ushort_t* __restrict__ wh,
    ushort_t* __restrict__ wp, float* __restrict__ biasP)
{
    int idx = blockIdx.x * 256 + threadIdx.x;
    if (idx < CVTQ) {
        int r = idx / 192;
        int c = (idx - r * 192) * 4;
        const float* src;
        ushort_t* dsth;
        if (r < MM) {
            src = x + (size_t)r * NC; dsth = xh + (size_t)r * NC + c;
        } else if (r < MM + 2304) {
            int rr = r - MM;
            src = w_qkv + (size_t)rr * NC; dsth = wh + (size_t)rr * NC + c;
        } else {
            int rr = r - MM - 2304;
            src = w_proj + (size_t)rr * NC; dsth = wp + (size_t)rr * NC + c;
        }
        float4 f = *(const float4*)(src + c);
        ushort4 hv = { (ushort_t)bf16_rne(f.x), (ushort_t)bf16_rne(f.y),
                       (ushort_t)bf16_rne(f.z), (ushort_t)bf16_rne(f.w) };
        *(ushort4*)dsth = hv;
    } else {
        int i = idx - CVTQ;
        if (i < BIASN) {
            int r = i & 3, l15 = (i >> 2) & 15, quad = (i >> 6) & 3;
            int t = i >> 8;
            int kt = t % 13; int t2 = t / 13;
            int qt = t2 % 13; int h = t2 / 13;
            int n = qt * 16 + quad * 4 + r;
            int m = kt * 16 + l15;
            float v = -1e30f;
            if (n < NN && m < NN) v = table[rel_index[n * NN + m] * NH + h];
            biasP[i] = v;
        }
    }
}

// ---------------------------------------------------------------------------
// bf16 MFMA mainloop, 128(M) x 256(N) tile, 4 waves (wm=M-half, wn=N-half).
// Per K-step: stage A 16KB + B 32KB, then 2 x (4+8 ds_read_b128, 32 MFMA).
// ---------------------------------------------------------------------------
__device__ __forceinline__ void gemm_mainloop(
    const ushort_t* __restrict__ A2, int sA,
    const ushort_t* __restrict__ B2, int sB,
    int m0, int n0, int kiters, ushort_t* Abuf, ushort_t* Bbuf, f32x4 acc[4][8])
{
    const int tid = threadIdx.x;
    const int w = tid >> 6, lane = tid & 63;
    const int wm = w & 1, wn = w >> 1;
    const int lr = lane >> 3, lc = lane & 7;
    const int gch = lc ^ lr;

    const ushort_t* Ag = A2 + (size_t)(m0 + w * 32 + lr) * sA + gch * 8;
    const ushort_t* Bg = B2 + (size_t)(n0 + w * 64 + lr) * sB + gch * 8;
    ushort_t* Al = Abuf + (w * 32) * 64;
    ushort_t* Bl = Bbuf + (w * 64) * 64;

    int aoff[4], boff[8];
    const int quad = lane >> 4, l15 = lane & 15;
    #pragma unroll
    for (int t = 0; t < 4; t++) {
        int ra = wm * 64 + t * 16 + l15;
        aoff[t] = ra * 64 + ((quad ^ (ra & 7)) << 3);
    }
    #pragma unroll
    for (int j = 0; j < 8; j++) {
        int rb = wn * 128 + j * 16 + l15;
        boff[j] = rb * 64 + ((quad ^ (rb & 7)) << 3);
    }

    for (int ks = 0; ks < kiters; ks++) {
        __syncthreads();
        #pragma unroll
        for (int it = 0; it < 4; it++)
            gld16(Al + it * 8 * 64, Ag + (size_t)it * 8 * sA);
        #pragma unroll
        for (int it = 0; it < 8; it++)
            gld16(Bl + it * 8 * 64, Bg + (size_t)it * 8 * sB);
        __syncthreads();
        #pragma unroll
        for (int k0 = 0; k0 < 2; k0++) {
            U128 af[4], bf[8];
            #pragma unroll
            for (int t = 0; t < 4; t++)
                af[t].u = *(const uint4*)&Abuf[aoff[t] ^ (k0 << 5)];
            #pragma unroll
            for (int j = 0; j < 8; j++)
                bf[j].u = *(const uint4*)&Bbuf[boff[j] ^ (k0 << 5)];
            #pragma unroll
            for (int i = 0; i < 4; i++)
                #pragma unroll
                for (int j = 0; j < 8; j++)
                    acc[i][j] = __builtin_amdgcn_mfma_f32_16x16x32_bf16(
                        af[i].s, bf[j].s, acc[i][j], 0, 0, 0);
        }
        Ag += 64; Bg += 64;
    }
}

// XCD-bijective chunked remap: consecutive f within one XCD.
__device__ __forceinline__ int xcd_remap(int bid, int nwg) {
    int q8 = nwg >> 3, r8 = nwg & 7;
    int xcd = bid & 7, loc = bid >> 3;
    return (xcd < r8 ? xcd * (q8 + 1) : r8 * (q8 + 1) + (xcd - r8) * q8) + loc;
}

// GEMM1: xh[MR,768] * wh[2304,768]^T -> qbf (scaled), kbf, vbf. 891 blocks.
__global__ __launch_bounds__(256, 2) void gemm_qkv_mfma(
    const ushort_t* __restrict__ A2, const ushort_t* __restrict__ B2,
    ushort_t* __restrict__ qbf, ushort_t* __restrict__ kbf,
    ushort_t* __restrict__ vbf)
{
    __shared__ ushort_t Abuf[128 * 64];
    __shared__ ushort_t Bbuf[256 * 64];
    f32x4 acc[4][8];
    f32x4 z = {0.f, 0.f, 0.f, 0.f};
    #pragma unroll
    for (int i = 0; i < 4; i++)
        #pragma unroll
        for (int j = 0; j < 8; j++) acc[i][j] = z;

    int f = xcd_remap(blockIdx.x, 891);
    int mt_ = f / 9, nt_ = f - mt_ * 9;
    const int m0 = mt_ * 128, n0 = nt_ * 256;
    gemm_mainloop(A2, NC, B2, NC, m0, n0, 12, Abuf, Bbuf, acc);

    __syncthreads();                         // Abuf free for reuse as scratch

    const int tid = threadIdx.x;
    const int w = tid >> 6, lane = tid & 63;
    const int wm = w & 1, wn = w >> 1;
    const int quad = lane >> 4, l15 = lane & 15;

    // per-wave LDS transpose scratch: 16 rows x 64 cols, stride 72 ushorts
    ushort_t* Sw = Abuf + w * 1152;
    const int orow = lane >> 2;
    const int dch = (lane & 3) << 3;         // 0,8,16,24
    #pragma unroll
    for (int mt = 0; mt < 4; mt++) {
        int m = m0 + wm * 64 + mt * 16 + orow;
        int b_ = m / NN, n_ = m - b_ * NN;
        bool mv = (m < MM);
        #pragma unroll
        for (int g = 0; g < 2; g++) {        // two 64-col groups of the 128-span
            int cg = n0 + wn * 128 + g * 64;
            int tq = cg / NC;
            int wi = cg - tq * NC;
            int hh = wi >> 6;
            ushort_t* dst = (tq == 0) ? qbf : (tq == 1) ? kbf : vbf;
            float scale = (tq == 0) ? 0.125f : 1.0f;
            #pragma unroll
            for (int nt = 0; nt < 4; nt++)
                #pragma unroll
                for (int r = 0; r < 4; r++)
                    Sw[(quad * 4 + r) * 72 + nt * 16 + l15] =
                        (ushort_t)bf16_rne(acc[mt][g * 4 + nt][r] * scale);
            if (mv) {
                size_t rb = ((size_t)(b_ * NH + hh) * NN + n_) * HD;
                uint4 v0 = *(const uint4*)&Sw[orow * 72 + dch];
                uint4 v1 = *(const uint4*)&Sw[orow * 72 + dch + 32];
                *(uint4*)&dst[rb + dch] = v0;
                *(uint4*)&dst[rb + dch + 32] = v1;
            }
        }
    }
}

// GEMM2: ab[MR,768] * wp[768,768]^T + bias -> out fp32. 297 blocks.
__global__ __launch_bounds__(256, 2) void gemm_proj_mfma(
    const ushort_t* __restrict__ A2, const ushort_t* __restrict__ B2,
    const float* __restrict__ bias, float* __restrict__ out)
{
    __shared__ ushort_t Abuf[128 * 64];
    __shared__ ushort_t Bbuf[256 * 64];
    f32x4 acc[4][8];
    f32x4 z = {0.f, 0.f, 0.f, 0.f};
    #pragma unroll
    for (int i = 0; i < 4; i++)
        #pragma unroll
        for (int j = 0; j < 8; j++) acc[i][j] = z;

    int f = xcd_remap(blockIdx.x, 297);
    int mt_ = f / 3, nt_ = f - mt_ * 3;
    const int m0 = mt_ * 128, n0 = nt_ * 256;
    gemm_mainloop(A2, NC, B2, NC, m0, n0, 12, Abuf, Bbuf, acc);

    const int tid = threadIdx.x;
    const int w = tid >> 6, lane = tid & 63;
    const int wm = w & 1, wn = w >> 1;
    const int quad = lane >> 4, l15 = lane & 15;
    #pragma unroll
    for (int nt = 0; nt < 8; nt++) {
        int col = n0 + wn * 128 + nt * 16 + l15;
        float bi = bias[col];
        #pragma unroll
        for (int mt = 0; mt < 4; mt++) {
            #pragma unroll
            for (int r = 0; r < 4; r++) {
                int m = m0 + wm * 64 + mt * 16 + quad * 4 + r;
                if (m < MM)
                    out[(size_t)m * NC + col] = acc[mt][nt][r] + bi;
            }
        }
    }
}

// ---------------------------------------------------------------------------
// MFMA attention. grid 768 x 256 threads (4 waves). One block per (b,h).
// K reg-staged into LDS (swizzled ds_write_b128); QK^T reads ds_read_b128.
// LDS 79872 B -> 2 blocks/CU.  (unchanged from r8 -- measured good)
// ---------------------------------------------------------------------------
__global__ __launch_bounds__(256) void attn_mfma(
    const ushort_t* __restrict__ qbf, const ushort_t* __restrict__ kbf,
    const ushort_t* __restrict__ vbf, const float* __restrict__ biasP,
    ushort_t* __restrict__ ab)
{
    __shared__ ushort_t Kl[NP * 64];         // 26624 B, GEMM-swizzle layout
    __shared__ ushort_t Vt[64 * PS];         // Vt[d][key], 26624 B
    __shared__ ushort_t Pl[4][16 * PS];      // per-wave P / V-stage / O-transpose

    const int bh = blockIdx.x;
    const int b = bh / NH, h = bh % NH;
    const int tid = threadIdx.x;
    const int w = tid >> 6, lane = tid & 63;
    const int quad = lane >> 4, l15 = lane & 15;
    const size_t base = (size_t)bh * (NN * HD);
    const ushort_t* kg = kbf + base;
    const ushort_t* vg = vbf + base;
    const ushort_t* qg = qbf + base;

    // ---- K stage: global -> reg -> swizzled LDS ----
    for (int idx = tid; idx < NP * 8; idx += 256) {
        int row = idx >> 3, ch = idx & 7;
        int srow = (row < NN) ? row : (NN - 1);
        uint4 val = *(const uint4*)(kg + (size_t)srow * HD + ch * 8);
        *(uint4*)&Kl[row * 64 + ((ch ^ (row & 7)) << 3)] = val;
    }

    // ---- stage V row-major coalesced, then LDS->LDS transpose into Vt ----
    ushort_t* Vstage = &Pl[0][0];            // 208*64 ushorts = Pl exactly
    for (int idx = tid; idx < NP * 8; idx += 256) {
        int row = idx >> 3, ch = idx & 7;
        uint4 val = {0u, 0u, 0u, 0u};
        if (row < NN) val = *(const uint4*)(vg + (size_t)row * HD + ch * 8);
        *(uint4*)&Vstage[row * HD + ch * 8] = val;
    }
    __syncthreads();                         // Kl + Vstage complete
    for (int task = tid; task < 64 * 26; task += 256) {
        int d = task & 63, kc = task >> 6;
        ushort_t tmp[8];
        #pragma unroll
        for (int j = 0; j < 8; j++)
            tmp[j] = Vstage[(kc * 8 + j) * HD + d];
        uint4 u;
        u.x = (unsigned)tmp[0] | ((unsigned)tmp[1] << 16);
        u.y = (unsigned)tmp[2] | ((unsigned)tmp[3] << 16);
        u.z = (unsigned)tmp[4] | ((unsigned)tmp[5] << 16);
        u.w = (unsigned)tmp[6] | ((unsigned)tmp[7] << 16);
        *(uint4*)&Vt[d * PS + kc * 8] = u;
    }
    __syncthreads();                         // Vt ready; Pl free

    const int ksl = (quad ^ (l15 & 7)) << 3; // K fragment slot (matches stage)

    #pragma unroll
    for (int rep = 0; rep < 4; rep++) {
        int qt = w + rep * 4;
        if (qt > 12) break;
        const int q0 = qt * 16;

        int qrow = q0 + l15; if (qrow > NN - 1) qrow = NN - 1;
        U128 qf0, qf1;
        qf0.u = *(const uint4*)(qg + (size_t)qrow * HD + quad * 8);
        qf1.u = *(const uint4*)(qg + (size_t)qrow * HD + 32 + quad * 8);

        // S init from biasP: 13 independent float4 loads
        f32x4 S[13];
        const float* bp = biasP + ((size_t)(h * 13 + qt) * 13) * 256 + (quad << 6) + (l15 << 2);
        #pragma unroll
        for (int kt = 0; kt < 13; kt++) {
            float4 bv = *(const float4*)(bp + kt * 256);
            S[kt][0] = bv.x; S[kt][1] = bv.y; S[kt][2] = bv.z; S[kt][3] = bv.w;
        }

        // QK^T: K fragments from LDS (conflict-free GEMM pattern)
        #pragma unroll
        for (int kt = 0; kt < 13; kt++) {
            int ro = (kt * 16 + l15) * 64 + ksl;
            U128 k0, k1;
            k0.u = *(const uint4*)&Kl[ro];
            k1.u = *(const uint4*)&Kl[ro ^ 32];
            S[kt] = __builtin_amdgcn_mfma_f32_16x16x32_bf16(qf0.s, k0.s, S[kt], 0, 0, 0);
            S[kt] = __builtin_amdgcn_mfma_f32_16x16x32_bf16(qf1.s, k1.s, S[kt], 0, 0, 0);
        }

        // softmax (rows quad*4+r over 16 l15 lanes x 13 tiles)
        ushort_t* P = Pl[w];
        #pragma unroll
        for (int r = 0; r < 4; r++) {
            float mx = S[0][r];
            #pragma unroll
            for (int kt = 1; kt < 13; kt++) mx = fmaxf(mx, S[kt][r]);
            mx = fmaxf(mx, __shfl_xor(mx, 1));
            mx = fmaxf(mx, __shfl_xor(mx, 2));
            mx = fmaxf(mx, __shfl_xor(mx, 4));
            mx = fmaxf(mx, __shfl_xor(mx, 8));
            float sum = 0.f;
            #pragma unroll
            for (int kt = 0; kt < 13; kt++) {
                float e = __expf(S[kt][r] - mx);
                S[kt][r] = e;
                sum += e;
            }
            sum += __shfl_xor(sum, 1);
            sum += __shfl_xor(sum, 2);
            sum += __shfl_xor(sum, 4);
            sum += __shfl_xor(sum, 8);
            float inv = 1.0f / sum;
            int prow = quad * 4 + r;
            #pragma unroll
            for (int kt = 0; kt < 13; kt++)
                P[prow * PS + kt * 16 + l15] = (ushort_t)bf16_rne(S[kt][r] * inv);
        }

        // PV: 7 chunks of 32 keys; chunk 6 keys 208..223 masked to 0.
        f32x4 O[4];
        f32x4 z4 = {0.f, 0.f, 0.f, 0.f};
        #pragma unroll
        for (int dt = 0; dt < 4; dt++) O[dt] = z4;
        #pragma unroll
        for (int ks = 0; ks < 7; ks++) {
            int pc = ks * 32 + quad * 8;
            bool vld = (pc < NP);
            int pcc = vld ? pc : 0;
            U128 pf;
            pf.u = *(const uint4*)&P[l15 * PS + pcc];
            if (!vld) { pf.u.x = 0u; pf.u.y = 0u; pf.u.z = 0u; pf.u.w = 0u; }
            #pragma unroll
            for (int dt = 0; dt < 4; dt++) {
                U128 vf;
                vf.u = *(const uint4*)&Vt[(dt * 16 + l15) * PS + pcc];
                O[dt] = __builtin_amdgcn_mfma_f32_16x16x32_bf16(pf.s, vf.s, O[dt], 0, 0, 0);
            }
        }

        // epilogue: transpose O through wave-private LDS, emit b128 bf16 hi
        float* Osh = (float*)&Pl[w][0];      // stride 68 floats
        #pragma unroll
        for (int dt = 0; dt < 4; dt++)
            #pragma unroll
            for (int r = 0; r < 4; r++)
                Osh[(quad * 4 + r) * 68 + dt * 16 + l15] = O[dt][r];
        int orow = lane >> 2;
        int d0 = (lane & 3) << 4;
        int q = q0 + orow;
        if (q < NN) {
            unsigned hiw[8];
            #pragma unroll
            for (int k4 = 0; k4 < 4; k4++) {
                float4 f = *(const float4*)&Osh[orow * 68 + d0 + k4 * 4];
                unsigned h0 = bf16_rne(f.x), h1 = bf16_rne(f.y);
                unsigned h2 = bf16_rne(f.z), h3 = bf16_rne(f.w);
                hiw[k4 * 2]     = h0 | (h1 << 16);
                hiw[k4 * 2 + 1] = h2 | (h3 << 16);
            }
            size_t baseo = ((size_t)b * NN + q) * NC + h * HD + d0;
            uint4 hA = {hiw[0], hiw[1], hiw[2], hiw[3]};
            uint4 hB = {hiw[4], hiw[5], hiw[6], hiw[7]};
            *(uint4*)&ab[baseo] = hA;
            *(uint4*)&ab[baseo + 8] = hB;
        }
    }
}

// ---------------------------------------------------------------------------
extern "C" void kernel_launch(void* const* d_in, const int* in_sizes, int n_in,
                              void* d_out, int out_size, void* d_ws, size_t ws_size,
                              hipStream_t stream)
{
    const float* x        = (const float*)d_in[0];
    const float* table    = (const float*)d_in[1];
    const float* w_qkv    = (const float*)d_in[2];
    const float* w_proj   = (const float*)d_in[3];
    const float* b_proj   = (const float*)d_in[4];
    const int*   rel_idx  = (const int*)d_in[5];
    float* out = (float*)d_out;

    ushort_t* xh  = (ushort_t*)d_ws;                        // MR*768
    ushort_t* wh  = xh + (size_t)MR * NC;                   // 2304*768
    ushort_t* wp  = wh + (size_t)2304 * NC;                 // 768*768
    ushort_t* ab  = wp + (size_t)768 * NC;                  // MR*768
    ushort_t* qbf = ab + (size_t)MR * NC;                   // SZQ each
    ushort_t* kbf = qbf + SZQ;
    ushort_t* vbf = kbf + SZQ;
    float* biasP  = (float*)(vbf + SZQ);                    // BIASN f32

    const int ptot = CVTQ + BIASN;
    prepare<<<(ptot + 255) / 256, 256, 0, stream>>>(
        x, w_qkv, w_proj, table, rel_idx, xh, wh, wp, biasP);

    gemm_qkv_mfma<<<891, 256, 0, stream>>>(xh, wh, qbf, kbf, vbf);
    attn_mfma<<<768, 256, 0, stream>>>(qbf, kbf, vbf, biasP, ab);
    gemm_proj_mfma<<<297, 256, 0, stream>>>(ab, wp, b_proj, out);
}